// Round 1
// baseline (203.284 us; speedup 1.0000x reference)
//
#include <hip/hip_runtime.h>
#include <hip/hip_bf16.h>
#include <math.h>

#define NDIM 768
#define NHEADS 12
#define HD 64
#define SEQ 1024
#define BATCH 8
#define MROWS (BATCH * SEQ)          // 8192
#define SQRT_DIM 27.712812921102035f // 1/SCALE_PARAM_INIT
#define LOG2E 1.4426950408889634f

typedef unsigned short u16;
typedef unsigned int u32;
typedef __attribute__((ext_vector_type(8))) short short8;   // 8 bf16 = 4 VGPRs
typedef __attribute__((ext_vector_type(4))) short bf16x4;   // 4 bf16 = 2 VGPRs
typedef __attribute__((ext_vector_type(4))) float f32x4;
typedef __attribute__((ext_vector_type(16))) float f32x16;

#define MFMA16(a, b, c) __builtin_amdgcn_mfma_f32_16x16x32_bf16(a, b, c, 0, 0, 0)
#define MFMA32(a, b, c) __builtin_amdgcn_mfma_f32_32x32x16_bf16(a, b, c, 0, 0, 0)

#if __has_builtin(__builtin_amdgcn_exp2f)
#define EXP2(x) __builtin_amdgcn_exp2f(x)
#else
#define EXP2(x) exp2f(x)
#endif

__device__ inline u16 f2bf(float f) {
    __hip_bfloat16 h = __float2bfloat16(f);
    return *reinterpret_cast<u16*>(&h);
}

// RNE round a,b to bf16 and pack into one u32 (a = low half). No NaN check —
// callers guarantee finite inputs.
__device__ inline u32 rne_pack(float a, float b) {
    u32 ua = __builtin_bit_cast(u32, a), ub = __builtin_bit_cast(u32, b);
    ua = (ua + 0x7fffu + ((ua >> 16) & 1u)) >> 16;
    ub = (ub + 0x7fffu + ((ub >> 16) & 1u)) >> 16;
    return (ub << 16) | ua;
}

// async 16B global->LDS. LDS dest is wave-uniform base; HW adds lane*16.
__device__ inline void gl2lds16(const void* g, void* l) {
    __builtin_amdgcn_global_load_lds((const __attribute__((address_space(1))) void*)g,
                                     (__attribute__((address_space(3))) void*)l, 16, 0, 0);
}

// compiler-fenced raw barrier (NO vmcnt drain — that is the whole point)
__device__ inline void bar() {
    asm volatile("" ::: "memory");
    __builtin_amdgcn_s_barrier();
    asm volatile("" ::: "memory");
}
#define LGKM0 asm volatile("s_waitcnt lgkmcnt(0)" ::: "memory")

// ---------------------------------------------------------------------------
// One fused cast kernel: x (6144 blocks) + Wq/Wk/Wv -> Wqkv, Wo -> Wob.
// ---------------------------------------------------------------------------
__global__ __launch_bounds__(256) void castall(const float* __restrict__ x,
                                               const float* __restrict__ Wq,
                                               const float* __restrict__ Wk,
                                               const float* __restrict__ Wv,
                                               const float* __restrict__ Wo,
                                               u16* __restrict__ xb,
                                               u16* __restrict__ Wqkv,
                                               u16* __restrict__ Wob) {
    const int WB = (NDIM * NDIM) / 1024; // 576 blocks per weight
    int blk = blockIdx.x;
    const float* s;
    u16* d;
    int base;
    if (blk < 6144) {
        s = x; d = xb; base = blk * 1024;
    } else {
        int wsel = (blk - 6144) / WB, r = (blk - 6144) % WB;
        base = r * 1024;
        if (wsel == 0)      { s = Wq; d = Wqkv; }
        else if (wsel == 1) { s = Wk; d = Wqkv + NDIM * NDIM; }
        else if (wsel == 2) { s = Wv; d = Wqkv + 2 * NDIM * NDIM; }
        else                { s = Wo; d = Wob; }
    }
    int i = base + threadIdx.x * 4;
    float4 v = *(const float4*)(s + i);
    uint2 o = make_uint2(rne_pack(v.x, v.y), rne_pack(v.z, v.w));
    *(uint2*)(d + i) = o;
}

// ---------------------------------------------------------------------------
// 256x256 / BK=64 / 8-wave 8-phase GEMM (T3+T4+T5 template) for the fused
// QKV projection: C = A[8192,768] @ B[2304,768]^T with fused cosine-norm
// (Q/K) and transposed-V epilogue.
//   - LDS 128 KiB: 2 dbuf x 2 halves x 128 rows x 64 k x {A,B}, 8-slot XOR
//     swizzle S(r,kc) = r*8 + (kc ^ (r&7)), linear gl2lds dest with
//     pre-swizzled global source (both-sides-or-neither rule).
//   - 4 phases per K-tile: {ds-read subtile || stage 1 half-tile} -> bar ->
//     lgkmcnt(0) -> setprio(1) 16xMFMA setprio(0) -> bar.
//   - counted vmcnt(4) ONCE per K-tile (phase 4); never 0 in steady state.
//     Staging order per tile T: P0:A(T+1)h0  P1:A(T+1)h1  P2:B(T+2)h0
//     P3:B(T+2)h1 -> at P3, loads newer than A(T+1)h1 = B(T+2)h0/h1 = 4.
// ---------------------------------------------------------------------------
__global__ __launch_bounds__(512, 2) void gemm256_qkv(const u16* __restrict__ A,
                                                      const u16* __restrict__ B,
                                                      u16* __restrict__ Vt,
                                                      const float* __restrict__ s_qk,
                                                      u16* __restrict__ Qdst,
                                                      u16* __restrict__ Kdst) {
    constexpr int K = NDIM;     // 768
    constexpr int NT = K / 64;  // 12 K-tiles
    __shared__ __align__(16) u16 As[2][2][128 * 64]; // [dbuf][half][r*8+slot]
    __shared__ __align__(16) u16 Bs[2][2][128 * 64];

    const int t = threadIdx.x;
    const int wave = t >> 6, lane = t & 63;
    const int quad = lane >> 4, l16 = lane & 15;
    const int wm = wave >> 2, wn = wave & 3; // 2 x 4 wave grid, 128x64 each
    const int fx = l16 & 7;                  // fragment-read XOR key

    // grid: 288 blocks = 32 M-tiles x 9 N-tiles; XCD-contiguous (288 % 8 == 0)
    const int wgid = (blockIdx.x & 7) * 36 + (blockIdx.x >> 3);
    const int bm = (wgid / 9) * 256;
    const int bn = (wgid % 9) * 256;

    f32x4 acc[8][4];
#pragma unroll
    for (int i = 0; i < 8; ++i)
#pragma unroll
        for (int j = 0; j < 4; ++j) acc[i][j] = (f32x4){0.f, 0.f, 0.f, 0.f};

    // half-tile stage: 128 rows x 64 k = 16 KB = 512 thr x 2 x 16B.
    // lane l of load `it` fills slot cb+l -> row (cb>>3)+(l>>3), slot-pos l&7,
    // which must hold chunk (l&7)^(l>>3)  (inverse of the read swizzle).
    const int srow = lane >> 3;
    const int schk = (lane & 7) ^ srow;
    auto stg = [&](const u16* src, u16* dst) {
#pragma unroll
        for (int it = 0; it < 2; ++it) {
            const int cb = it * 512 + wave * 64; // slot base, wave-uniform
            const int r = (cb >> 3) + srow;      // row 0..127
            gl2lds16(src + (size_t)r * K + schk * 8, (char*)dst + cb * 16);
        }
    };
    const u16* Ag = A + (size_t)bm * K;
    const u16* Bg = B + (size_t)bn * K;

    // prologue: tile0 {A,B} + tile1 {B}; wait tile0 (12 issued, 4 may fly)
    stg(Ag,                        As[0][0]);
    stg(Ag + (size_t)128 * K,      As[0][1]);
    stg(Bg,                        Bs[0][0]);
    stg(Bg + (size_t)128 * K,      Bs[0][1]);
    stg(Bg + 64,                   Bs[1][0]);
    stg(Bg + (size_t)128 * K + 64, Bs[1][1]);
    asm volatile("s_waitcnt vmcnt(4)" ::: "memory");
    bar();

    short8 a[4][2], b0[2][2], b1[2][2];
    const int rb0 = (wn & 1) * 64; // this wave's B-row base within its half

#pragma unroll 2
    for (int T = 0; T < NT; ++T) {
        const int db = T & 1;
        u16* Asl = As[db][wm];
        u16* Bsl = Bs[db][wn >> 1];
        const u16* An = Ag + (size_t)(T + 1) * 64;
        const u16* Bn = Bg + (size_t)(T + 2) * 64;

        // ---- P0: read A[mi0-3] + B[ni0-1]; stage A(T+1)h0; MFMA Q(0,0) ----
#pragma unroll
        for (int mi = 0; mi < 4; ++mi) {
            const int r = mi * 16 + l16;
#pragma unroll
            for (int kk = 0; kk < 2; ++kk)
                a[mi][kk] = *(const short8*)&Asl[(r * 8 + ((kk * 4 + quad) ^ fx)) * 8];
        }
#pragma unroll
        for (int ni = 0; ni < 2; ++ni) {
            const int r = rb0 + ni * 16 + l16;
#pragma unroll
            for (int kk = 0; kk < 2; ++kk)
                b0[ni][kk] = *(const short8*)&Bsl[(r * 8 + ((kk * 4 + quad) ^ fx)) * 8];
        }
        if (T + 1 < NT) stg(An, As[db ^ 1][0]);
        bar();
        LGKM0;
        __builtin_amdgcn_s_setprio(1);
#pragma unroll
        for (int kk = 0; kk < 2; ++kk)
#pragma unroll
            for (int mi = 0; mi < 4; ++mi)
#pragma unroll
                for (int ni = 0; ni < 2; ++ni)
                    acc[mi][ni] = MFMA16(a[mi][kk], b0[ni][kk], acc[mi][ni]);
        __builtin_amdgcn_s_setprio(0);
        bar();

        // ---- P1: read B[ni2-3]; stage A(T+1)h1; MFMA Q(0,1) ----
#pragma unroll
        for (int ni = 0; ni < 2; ++ni) {
            const int r = rb0 + (ni + 2) * 16 + l16;
#pragma unroll
            for (int kk = 0; kk < 2; ++kk)
                b1[ni][kk] = *(const short8*)&Bsl[(r * 8 + ((kk * 4 + quad) ^ fx)) * 8];
        }
        if (T + 1 < NT) stg(An + (size_t)128 * K, As[db ^ 1][1]);
        bar();
        LGKM0;
        __builtin_amdgcn_s_setprio(1);
#pragma unroll
        for (int kk = 0; kk < 2; ++kk)
#pragma unroll
            for (int mi = 0; mi < 4; ++mi)
#pragma unroll
                for (int ni = 0; ni < 2; ++ni)
                    acc[mi][ni + 2] = MFMA16(a[mi][kk], b1[ni][kk], acc[mi][ni + 2]);
        __builtin_amdgcn_s_setprio(0);
        bar();

        // ---- P2: read A[mi4-7]; stage B(T+2)h0; MFMA Q(1,1) ----
#pragma unroll
        for (int mi = 0; mi < 4; ++mi) {
            const int r = (mi + 4) * 16 + l16;
#pragma unroll
            for (int kk = 0; kk < 2; ++kk)
                a[mi][kk] = *(const short8*)&Asl[(r * 8 + ((kk * 4 + quad) ^ fx)) * 8];
        }
        if (T + 2 < NT) stg(Bn, Bs[db][0]);
        bar();
        LGKM0;
        __builtin_amdgcn_s_setprio(1);
#pragma unroll
        for (int kk = 0; kk < 2; ++kk)
#pragma unroll
            for (int mi = 0; mi < 4; ++mi)
#pragma unroll
                for (int ni = 0; ni < 2; ++ni)
                    acc[mi + 4][ni + 2] = MFMA16(a[mi][kk], b1[ni][kk], acc[mi + 4][ni + 2]);
        __builtin_amdgcn_s_setprio(0);
        bar();

        // ---- P3: stage B(T+2)h1; MFMA Q(1,0); counted vmcnt; bar ----
        if (T + 2 < NT) stg(Bn + (size_t)128 * K, Bs[db][1]);
        bar();
        __builtin_amdgcn_s_setprio(1);
#pragma unroll
        for (int kk = 0; kk < 2; ++kk)
#pragma unroll
            for (int mi = 0; mi < 4; ++mi)
#pragma unroll
                for (int ni = 0; ni < 2; ++ni)
                    acc[mi + 4][ni] = MFMA16(a[mi][kk], b0[ni][kk], acc[mi + 4][ni]);
        __builtin_amdgcn_s_setprio(0);
        if (T + 2 < NT) {
            asm volatile("s_waitcnt vmcnt(4)" ::: "memory"); // tile T+1 resident
        } else {
            asm volatile("s_waitcnt vmcnt(0)" ::: "memory"); // epilogue drain
        }
        bar();
    }

    // ---- fused QKV epilogue (wave's 64 cols = exactly one head-group) ----
    const int cg = (bn + wn * 64) >> 6; // 0..35
    if (cg >= 2 * NHEADS) {
        // V path: transposed bf16 write into Vt
        const int h = cg - 2 * NHEADS;
#pragma unroll
        for (int mi = 0; mi < 8; ++mi)
#pragma unroll
            for (int ni = 0; ni < 4; ++ni)
#pragma unroll
                for (int r = 0; r < 4; ++r) {
                    const int row = bm + wm * 128 + mi * 16 + quad * 4 + r; // token
                    const int dd = ni * 16 + l16;
                    const int bb = row >> 10, n = row & 1023;
                    Vt[(((size_t)(bb * NHEADS + h) * HD + dd) << 10) + n] =
                        f2bf(acc[mi][ni][r]);
                }
    } else {
        const bool isq = cg < NHEADS;
        const int h = isq ? cg : cg - NHEADS;
        u16* dst = isq ? Qdst : Kdst;
        const float ex = isq ? 8.f * LOG2E : 1.f;
        float sq[4];
#pragma unroll
        for (int ni = 0; ni < 4; ++ni)
            sq[ni] = s_qk[h * HD + ni * 16 + l16] * SQRT_DIM * ex;
#pragma unroll
        for (int mi = 0; mi < 8; ++mi)
#pragma unroll
            for (int r = 0; r < 4; ++r) {
                float ss = 0.f;
#pragma unroll
                for (int ni = 0; ni < 4; ++ni) ss += acc[mi][ni][r] * acc[mi][ni][r];
                ss += __shfl_xor(ss, 1, 64);
                ss += __shfl_xor(ss, 2, 64);
                ss += __shfl_xor(ss, 4, 64);
                ss += __shfl_xor(ss, 8, 64);
                float inv = 1.f / fmaxf(sqrtf(ss), 1e-6f);
                const int row = bm + wm * 128 + mi * 16 + quad * 4 + r;
                const int bb = row >> 10, tok = row & 1023;
                u16* o = dst + ((size_t)(bb * NHEADS + h) * SEQ + tok) * HD;
#pragma unroll
                for (int ni = 0; ni < 4; ++ni)
                    o[ni * 16 + l16] = f2bf(acc[mi][ni][r] * sq[ni] * inv);
            }
    }
}

// ---------------------------------------------------------------------------
// bf16 MFMA GEMM: C = A[M,768] @ B[N,768]^T, fp32 accum. 128x128 tile,
// double-buffered BK=32 (one barrier/iter). Kept for the output projection
// (grid granularity: 384 blocks vs 96 at 256^2). EPI 0: fp32 C.
// ---------------------------------------------------------------------------
template <int EPI>
__global__ __launch_bounds__(256) void gemm_bf16(const u16* __restrict__ A,
                                                 const u16* __restrict__ B,
                                                 void* __restrict__ C, int N,
                                                 const float* __restrict__ s_qk,
                                                 u16* __restrict__ Qdst,
                                                 u16* __restrict__ Kdst,
                                                 int NX) {
    constexpr int K = NDIM;
    constexpr int NKT = K / 32; // 24 K-tiles
    __shared__ __align__(16) u16 As[2][4096]; // 8 KB per buffer
    __shared__ __align__(16) u16 Bs[2][4096];
    const int t = threadIdx.x;
    const int wave = t >> 6, lane = t & 63;
    const int quad = lane >> 4, l16 = lane & 15;
    const int wx = (wave & 1) * 64, wy = (wave >> 1) * 64;
    const int blk = blockIdx.x;
    const int xcd = blk & 7, local = blk >> 3;
    const int bm = (xcd * 8 + local / NX) * 128;
    const int bn = (local % NX) * 128;

    f32x4 acc[4][4];
#pragma unroll
    for (int i = 0; i < 4; ++i)
#pragma unroll
        for (int j = 0; j < 4; ++j) acc[i][j] = (f32x4){0.f, 0.f, 0.f, 0.f};

    const int srl = lane >> 2;
    const int skc = (lane & 3) ^ ((lane >> 3) & 3);
    auto stage = [&](int k0, int bsel) {
#pragma unroll
        for (int it = 0; it < 2; ++it) {
            const int cb = it * 256 + wave * 64;
            const int row = (cb >> 6) * 16 + srl;
            gl2lds16(A + (size_t)(bm + row) * K + k0 + skc * 8,
                     (char*)As[bsel] + cb * 16);
            gl2lds16(B + (size_t)(bn + row) * K + k0 + skc * 8,
                     (char*)Bs[bsel] + cb * 16);
        }
    };
    const int fxor = (l16 >> 1) & 3;

    stage(0, 0);
#pragma unroll
    for (int kt = 0; kt < NKT; ++kt) {
        __syncthreads();
        if (kt + 1 < NKT) stage((kt + 1) * 32, (kt + 1) & 1);
        const int b = kt & 1;
        short8 af[4], bfr[4];
#pragma unroll
        for (int i = 0; i < 4; ++i)
            af[i] = *(const short8*)&As[b][
                ((((wy >> 4) + i) * 64 + l16 * 4 + (quad ^ fxor)) * 8)];
#pragma unroll
        for (int j = 0; j < 4; ++j)
            bfr[j] = *(const short8*)&Bs[b][
                ((((wx >> 4) + j) * 64 + l16 * 4 + (quad ^ fxor)) * 8)];
#pragma unroll
        for (int i = 0; i < 4; ++i)
#pragma unroll
            for (int j = 0; j < 4; ++j) acc[i][j] = MFMA16(af[i], bfr[j], acc[i][j]);
    }

    if constexpr (EPI == 0) {
#pragma unroll
        for (int i = 0; i < 4; ++i)
#pragma unroll
            for (int j = 0; j < 4; ++j)
#pragma unroll
                for (int r = 0; r < 4; ++r) {
                    const int row = bm + wy + i * 16 + quad * 4 + r;
                    const int col = bn + wx + j * 16 + l16;
                    ((float*)C)[(size_t)row * N + col] = acc[i][j][r];
                }
    }
}

// ---------------------------------------------------------------------------
// MFMA flash attention, 32x32x16, no-max softmax. 256 threads = 4 waves;
// each wave owns 32 queries -> block = 128 queries; streams 64-key tiles.
// ---------------------------------------------------------------------------
__global__ __launch_bounds__(256) void attn_mfma(const u16* __restrict__ Qh,
                                                 const u16* __restrict__ Kh,
                                                 const u16* __restrict__ Vt,
                                                 u16* __restrict__ AO) {
    __shared__ __align__(16) u16 Ks[512 * 8];
    __shared__ __align__(16) u16 Vs[512 * 8];
    __shared__ __align__(16) u16 Ps[4 * 32 * 64]; // [wave][qrow][64], swizzled

    const int t = threadIdx.x;
    const int wave = t >> 6, lane = t & 63;
    const int l31 = lane & 31, half = lane >> 5;
    const int b = blockIdx.z, h = blockIdx.y, q0 = blockIdx.x * 128;
    const int bh = b * NHEADS + h;
    const u16* Kb = Kh + (size_t)bh * SEQ * HD;
    const u16* Vb = Vt + (size_t)bh * HD * SEQ;
    const int qb = q0 + wave * 32;
    const int pbase = wave * 2048 + l31 * 64;
    const int sw = (l31 & 15);

    short8 qf[4];
#pragma unroll
    for (int tt = 0; tt < 4; ++tt)
        qf[tt] = *(const short8*)(Qh + ((size_t)bh * SEQ + qb + l31) * HD +
                                  tt * 16 + half * 8);

    f32x16 o[2];
#pragma unroll
    for (int dt = 0; dt < 2; ++dt)
#pragma unroll
        for (int r = 0; r < 16; ++r) o[dt][r] = 0.f;
    float lp = 0.f;

    const int arl = lane >> 3;
    const int acc8 = (lane & 7) ^ arl;
    const int fx8 = l31 & 7;

    for (int j0 = 0; j0 < SEQ; j0 += 64) {
        __syncthreads();
#pragma unroll
        for (int it = 0; it < 2; ++it) {
            const int cb = it * 256 + wave * 64;
            const int r0 = (cb >> 6) * 8 + arl;
            gl2lds16(Kb + (size_t)(j0 + r0) * HD + acc8 * 8, (char*)Ks + cb * 16);
            gl2lds16(Vb + (size_t)r0 * SEQ + j0 + acc8 * 8, (char*)Vs + cb * 16);
        }
        asm volatile("s_waitcnt vmcnt(0)" ::: "memory");
        __syncthreads();

        // ---- S^T phase: 64 keys x 32 queries ----
#pragma unroll
        for (int kt = 0; kt < 2; ++kt) {
            f32x16 sa;
#pragma unroll
            for (int r = 0; r < 16; ++r) sa[r] = 0.f;
#pragma unroll
            for (int tt = 0; tt < 4; ++tt) {
                short8 kf = *(const short8*)&Ks[
                    (((kt * 4 + (l31 >> 3)) * 64) + fx8 * 8 +
                     ((2 * tt + half) ^ fx8)) * 8];
                sa = MFMA32(kf, qf[tt], sa);
            }
#pragma unroll
            for (int rg = 0; rg < 4; ++rg) {
                float p0 = EXP2(sa[rg * 4 + 0]);
                float p1 = EXP2(sa[rg * 4 + 1]);
                float p2 = EXP2(sa[rg * 4 + 2]);
                float p3 = EXP2(sa[rg * 4 + 3]);
                lp += (p0 + p1) + (p2 + p3);
                uint2 pk = make_uint2(rne_pack(p0, p1), rne_pack(p2, p3));
                const int u = kt * 8 + rg * 2 + half;
                *(uint2*)&Ps[pbase + (u ^ sw) * 4] = pk;
            }
        }

        // ---- PV phase: O^T += V^T @ P ----
#pragma unroll
        for (int k2 = 0; k2 < 4; ++k2) {
            const int u0 = k2 * 4 + half * 2;
            bf16x4 lo = *(const bf16x4*)&Ps[pbase + ((u0 + 0) ^ sw) * 4];
            bf16x4 hi = *(const bf16x4*)&Ps[pbase + ((u0 + 1) ^ sw) * 4];
            short8 pf = __builtin_shufflevector(lo, hi, 0, 1, 2, 3, 4, 5, 6, 7);
#pragma unroll
            for (int dt = 0; dt < 2; ++dt) {
                short8 vf = *(const short8*)&Vs[
                    (((dt * 4 + (l31 >> 3)) * 64) + fx8 * 8 +
                     ((2 * k2 + half) ^ fx8)) * 8];
                o[dt] = MFMA32(vf, pf, o[dt]);
            }
        }
    }

    const float invl = 1.f / (lp + __shfl_xor(lp, 32, 64));
    u16* ob = AO + (size_t)(b * SEQ + qb + l31) * NDIM + h * HD;
#pragma unroll
    for (int dt = 0; dt < 2; ++dt)
#pragma unroll
        for (int rg = 0; rg < 4; ++rg) {
            bf16x4 ok = {(short)f2bf(o[dt][rg * 4 + 0] * invl),
                         (short)f2bf(o[dt][rg * 4 + 1] * invl),
                         (short)f2bf(o[dt][rg * 4 + 2] * invl),
                         (short)f2bf(o[dt][rg * 4 + 3] * invl)};
            *(bf16x4*)(ob + dt * 32 + rg * 8 + half * 4) = ok;
        }
}

// ---------------------------------------------------------------------------
extern "C" void kernel_launch(void* const* d_in, const int* in_sizes, int n_in,
                              void* d_out, int out_size, void* d_ws, size_t ws_size,
                              hipStream_t stream) {
    const float* x    = (const float*)d_in[0];
    const float* Wq   = (const float*)d_in[1];
    const float* Wk   = (const float*)d_in[2];
    const float* Wv   = (const float*)d_in[3];
    const float* Wo   = (const float*)d_in[4];
    const float* s_qk = (const float*)d_in[5];
    float* out = (float*)d_out;

    char* w = (char*)d_ws;
    const size_t TE = (size_t)MROWS * NDIM;
    u16* xb   = (u16*)w;                    w += TE * 2;
    u16* Wqkv = (u16*)w;                    w += (size_t)3 * NDIM * NDIM * 2;
    u16* Wob  = (u16*)w;                    w += (size_t)NDIM * NDIM * 2;
    u16* Qh   = (u16*)w;                    w += TE * 2;
    u16* Kh   = (u16*)w;                    w += TE * 2;
    u16* Vt   = (u16*)w;                    w += TE * 2;
    u16* ao   = (u16*)w;

    castall<<<6144 + 4 * 576, 256, 0, stream>>>(x, Wq, Wk, Wv, Wo, xb, Wqkv, Wob);

    // Fused QKV projection: 256^2 8-phase template, 32x9 = 288 blocks
    gemm256_qkv<<<288, 512, 0, stream>>>(xb, Wqkv, Vt, s_qk, Qh, Kh);

    attn_mfma<<<dim3(SEQ / 128, NHEADS, BATCH), 256, 0, stream>>>(Qh, Kh, Vt, ao);

    // Output projection: NX = 768/128 = 6
    gemm_bf16<0><<<6 * 64, 256, 0, stream>>>(
        ao, Wob, out, NDIM, nullptr, nullptr, nullptr, 6);
}

// Round 2
// 192.391 us; speedup vs baseline: 1.0566x; 1.0566x over previous
//
#include <hip/hip_runtime.h>
#include <hip/hip_bf16.h>
#include <math.h>

#define NDIM 768
#define NHEADS 12
#define HD 64
#define SEQ 1024
#define BATCH 8
#define MROWS (BATCH * SEQ)          // 8192
#define SQRT_DIM 27.712812921102035f // 1/SCALE_PARAM_INIT
#define LOG2E 1.4426950408889634f

typedef unsigned short u16;
typedef unsigned int u32;
typedef __attribute__((ext_vector_type(8))) short short8;   // 8 bf16 = 4 VGPRs
typedef __attribute__((ext_vector_type(4))) short bf16x4;   // 4 bf16 = 2 VGPRs
typedef __attribute__((ext_vector_type(4))) float f32x4;
typedef __attribute__((ext_vector_type(16))) float f32x16;

#define MFMA16(a, b, c) __builtin_amdgcn_mfma_f32_16x16x32_bf16(a, b, c, 0, 0, 0)
#define MFMA32(a, b, c) __builtin_amdgcn_mfma_f32_32x32x16_bf16(a, b, c, 0, 0, 0)

#if __has_builtin(__builtin_amdgcn_exp2f)
#define EXP2(x) __builtin_amdgcn_exp2f(x)
#else
#define EXP2(x) exp2f(x)
#endif

__device__ inline u16 f2bf(float f) {
    __hip_bfloat16 h = __float2bfloat16(f);
    return *reinterpret_cast<u16*>(&h);
}

// RNE round a,b to bf16 and pack into one u32 (a = low half). No NaN check —
// callers guarantee finite inputs.
__device__ inline u32 rne_pack(float a, float b) {
    u32 ua = __builtin_bit_cast(u32, a), ub = __builtin_bit_cast(u32, b);
    ua = (ua + 0x7fffu + ((ua >> 16) & 1u)) >> 16;
    ub = (ub + 0x7fffu + ((ub >> 16) & 1u)) >> 16;
    return (ub << 16) | ua;
}

// async 16B global->LDS. LDS dest is wave-uniform base; HW adds lane*16.
__device__ inline void gl2lds16(const void* g, void* l) {
    __builtin_amdgcn_global_load_lds((const __attribute__((address_space(1))) void*)g,
                                     (__attribute__((address_space(3))) void*)l, 16, 0, 0);
}

// compiler-fenced raw barrier (NO vmcnt drain — that is the whole point)
__device__ inline void bar() {
    asm volatile("" ::: "memory");
    __builtin_amdgcn_s_barrier();
    asm volatile("" ::: "memory");
}
#define LGKM0 asm volatile("s_waitcnt lgkmcnt(0)" ::: "memory")
#define VM0   asm volatile("s_waitcnt vmcnt(0)" ::: "memory")

// ---------------------------------------------------------------------------
// One fused cast kernel: x (6144 blocks) + Wq/Wk/Wv -> Wqkv, Wo -> Wob.
// ---------------------------------------------------------------------------
__global__ __launch_bounds__(256) void castall(const float* __restrict__ x,
                                               const float* __restrict__ Wq,
                                               const float* __restrict__ Wk,
                                               const float* __restrict__ Wv,
                                               const float* __restrict__ Wo,
                                               u16* __restrict__ xb,
                                               u16* __restrict__ Wqkv,
                                               u16* __restrict__ Wob) {
    const int WB = (NDIM * NDIM) / 1024; // 576 blocks per weight
    int blk = blockIdx.x;
    const float* s;
    u16* d;
    int base;
    if (blk < 6144) {
        s = x; d = xb; base = blk * 1024;
    } else {
        int wsel = (blk - 6144) / WB, r = (blk - 6144) % WB;
        base = r * 1024;
        if (wsel == 0)      { s = Wq; d = Wqkv; }
        else if (wsel == 1) { s = Wk; d = Wqkv + NDIM * NDIM; }
        else if (wsel == 2) { s = Wv; d = Wqkv + 2 * NDIM * NDIM; }
        else                { s = Wo; d = Wob; }
    }
    int i = base + threadIdx.x * 4;
    float4 v = *(const float4*)(s + i);
    uint2 o = make_uint2(rne_pack(v.x, v.y), rne_pack(v.z, v.w));
    *(uint2*)(d + i) = o;
}

// ---------------------------------------------------------------------------
// 256x256 / BK=64 / 8-wave 8-phase GEMM (T3+T4+T5 template) for the fused
// QKV projection: C = A[8192,768] @ B[2304,768]^T with fused cosine-norm
// (Q/K) and transposed-V epilogue.
//
// Scheduling: 288 output tiles don't fit 256 CUs at 1 blk/CU (128 KiB LDS +
// 128-reg acc cap us there), so a uniform 288-block grid costs 2 rounds at
// 56% eff (measured r1: 58.6 us = 2x29.3). Instead grid = 384:
//   blk 0..255  : full 256^2 tiles over N-tiles 0..7 (exactly one round)
//   blk 256..383: 128x128 quarter-tiles over the last N-strip (cols
//                 2048..2303 = V heads 8..11), simple dbuf loop; they fill
//                 in as the fulls drain -> tail ~ T_solo/3, not a full round.
// ---------------------------------------------------------------------------
__global__ __launch_bounds__(512, 2) void gemm256_qkv(const u16* __restrict__ A,
                                                      const u16* __restrict__ B,
                                                      u16* __restrict__ Vt,
                                                      const float* __restrict__ s_qk,
                                                      u16* __restrict__ Qdst,
                                                      u16* __restrict__ Kdst) {
    constexpr int K = NDIM;     // 768
    constexpr int NT = K / 64;  // 12 K-tiles
    __shared__ __align__(16) u16 As[2][2][128 * 64]; // [dbuf][half][r*8+slot]
    __shared__ __align__(16) u16 Bs[2][2][128 * 64];

    const int t = threadIdx.x;
    const int wave = t >> 6, lane = t & 63;
    const int quad = lane >> 4, l16 = lane & 15;
    const int fx = l16 & 7;                  // fragment-read XOR key
    const int blk = blockIdx.x;

    // half-tile stage: 128 rows x 64 k = 16 KB = 512 thr x 2 x 16B.
    // lane l of load `it` fills slot cb+l -> row (cb>>3)+(l>>3), slot-pos l&7,
    // which must hold chunk (l&7)^(l>>3)  (inverse of the read swizzle).
    const int srow = lane >> 3;
    const int schk = (lane & 7) ^ srow;
    auto stg = [&](const u16* src, u16* dst) {
#pragma unroll
        for (int it = 0; it < 2; ++it) {
            const int cb = it * 512 + wave * 64; // slot base, wave-uniform
            const int r = (cb >> 3) + srow;      // row 0..127
            gl2lds16(src + (size_t)r * K + schk * 8, (char*)dst + cb * 16);
        }
    };

    if (blk < 256) {
        // =================== full 256^2 8-phase path ===================
        const int wm = wave >> 2, wn = wave & 3; // 2 x 4 wave grid, 128x64 each
        const int xcd = blk & 7, local = blk >> 3;            // 0..31
        const int bm = xcd * 1024 + (local >> 3) * 256;       // 4 M-tiles/XCD
        const int bn = (local & 7) * 256;                     // N-tiles 0..7

        f32x4 acc[8][4];
#pragma unroll
        for (int i = 0; i < 8; ++i)
#pragma unroll
            for (int j = 0; j < 4; ++j) acc[i][j] = (f32x4){0.f, 0.f, 0.f, 0.f};

        const u16* Ag = A + (size_t)bm * K;
        const u16* Bg = B + (size_t)bn * K;

        // prologue: tile0 {A,B} + tile1 {B}; wait tile0 (12 issued, 4 may fly)
        stg(Ag,                        As[0][0]);
        stg(Ag + (size_t)128 * K,      As[0][1]);
        stg(Bg,                        Bs[0][0]);
        stg(Bg + (size_t)128 * K,      Bs[0][1]);
        stg(Bg + 64,                   Bs[1][0]);
        stg(Bg + (size_t)128 * K + 64, Bs[1][1]);
        asm volatile("s_waitcnt vmcnt(4)" ::: "memory");
        bar();

        short8 a[4][2], b0[2][2], b1[2][2];
        const int rb0 = (wn & 1) * 64; // this wave's B-row base within its half

#pragma unroll 2
        for (int T = 0; T < NT; ++T) {
            const int db = T & 1;
            u16* Asl = As[db][wm];
            u16* Bsl = Bs[db][wn >> 1];
            const u16* An = Ag + (size_t)(T + 1) * 64;
            const u16* Bn = Bg + (size_t)(T + 2) * 64;

            // ---- P0: read A[mi0-3] + B[ni0-1]; stage A(T+1)h0; MFMA Q(0,0) ----
#pragma unroll
            for (int mi = 0; mi < 4; ++mi) {
                const int r = mi * 16 + l16;
#pragma unroll
                for (int kk = 0; kk < 2; ++kk)
                    a[mi][kk] = *(const short8*)&Asl[(r * 8 + ((kk * 4 + quad) ^ fx)) * 8];
            }
#pragma unroll
            for (int ni = 0; ni < 2; ++ni) {
                const int r = rb0 + ni * 16 + l16;
#pragma unroll
                for (int kk = 0; kk < 2; ++kk)
                    b0[ni][kk] = *(const short8*)&Bsl[(r * 8 + ((kk * 4 + quad) ^ fx)) * 8];
            }
            if (T + 1 < NT) stg(An, As[db ^ 1][0]);
            bar();
            LGKM0;
            __builtin_amdgcn_s_setprio(1);
#pragma unroll
            for (int kk = 0; kk < 2; ++kk)
#pragma unroll
                for (int mi = 0; mi < 4; ++mi)
#pragma unroll
                    for (int ni = 0; ni < 2; ++ni)
                        acc[mi][ni] = MFMA16(a[mi][kk], b0[ni][kk], acc[mi][ni]);
            __builtin_amdgcn_s_setprio(0);
            bar();

            // ---- P1: read B[ni2-3]; stage A(T+1)h1; MFMA Q(0,1) ----
#pragma unroll
            for (int ni = 0; ni < 2; ++ni) {
                const int r = rb0 + (ni + 2) * 16 + l16;
#pragma unroll
                for (int kk = 0; kk < 2; ++kk)
                    b1[ni][kk] = *(const short8*)&Bsl[(r * 8 + ((kk * 4 + quad) ^ fx)) * 8];
            }
            if (T + 1 < NT) stg(An + (size_t)128 * K, As[db ^ 1][1]);
            bar();
            LGKM0;
            __builtin_amdgcn_s_setprio(1);
#pragma unroll
            for (int kk = 0; kk < 2; ++kk)
#pragma unroll
                for (int mi = 0; mi < 4; ++mi)
#pragma unroll
                    for (int ni = 0; ni < 2; ++ni)
                        acc[mi][ni + 2] = MFMA16(a[mi][kk], b1[ni][kk], acc[mi][ni + 2]);
            __builtin_amdgcn_s_setprio(0);
            bar();

            // ---- P2: read A[mi4-7]; stage B(T+2)h0; MFMA Q(1,1) ----
#pragma unroll
            for (int mi = 0; mi < 4; ++mi) {
                const int r = (mi + 4) * 16 + l16;
#pragma unroll
                for (int kk = 0; kk < 2; ++kk)
                    a[mi][kk] = *(const short8*)&Asl[(r * 8 + ((kk * 4 + quad) ^ fx)) * 8];
            }
            if (T + 2 < NT) stg(Bn, Bs[db][0]);
            bar();
            LGKM0;
            __builtin_amdgcn_s_setprio(1);
#pragma unroll
            for (int kk = 0; kk < 2; ++kk)
#pragma unroll
                for (int mi = 0; mi < 4; ++mi)
#pragma unroll
                    for (int ni = 0; ni < 2; ++ni)
                        acc[mi + 4][ni + 2] = MFMA16(a[mi][kk], b1[ni][kk], acc[mi + 4][ni + 2]);
            __builtin_amdgcn_s_setprio(0);
            bar();

            // ---- P3: stage B(T+2)h1; MFMA Q(1,0); counted vmcnt; bar ----
            if (T + 2 < NT) stg(Bn + (size_t)128 * K, Bs[db][1]);
            bar();
            __builtin_amdgcn_s_setprio(1);
#pragma unroll
            for (int kk = 0; kk < 2; ++kk)
#pragma unroll
                for (int mi = 0; mi < 4; ++mi)
#pragma unroll
                    for (int ni = 0; ni < 2; ++ni)
                        acc[mi + 4][ni] = MFMA16(a[mi][kk], b0[ni][kk], acc[mi + 4][ni]);
            __builtin_amdgcn_s_setprio(0);
            if (T + 2 < NT) {
                asm volatile("s_waitcnt vmcnt(4)" ::: "memory"); // tile T+1 resident
            } else {
                VM0; // drains A(NT-1) too (last two iters)
            }
            bar();
        }

        // ---- fused QKV epilogue (wave's 64 cols = exactly one head-group) ----
        const int cg = (bn + wn * 64) >> 6; // 0..31 here
        if (cg >= 2 * NHEADS) {
            // V path: transposed bf16 write, 4 consecutive tokens packed -> 8B
            const int h = cg - 2 * NHEADS;
#pragma unroll
            for (int mi = 0; mi < 8; ++mi) {
                const int row = bm + wm * 128 + mi * 16 + quad * 4; // token base
                const int bb = row >> 10, n0 = row & 1023;
#pragma unroll
                for (int ni = 0; ni < 4; ++ni) {
                    const int dd = ni * 16 + l16;
                    uint2 pk = make_uint2(rne_pack(acc[mi][ni][0], acc[mi][ni][1]),
                                          rne_pack(acc[mi][ni][2], acc[mi][ni][3]));
                    *(uint2*)(Vt + (((size_t)(bb * NHEADS + h) * HD + dd) << 10) + n0) = pk;
                }
            }
        } else {
            const bool isq = cg < NHEADS;
            const int h = isq ? cg : cg - NHEADS;
            u16* dst = isq ? Qdst : Kdst;
            const float ex = isq ? 8.f * LOG2E : 1.f;
            float sq[4];
#pragma unroll
            for (int ni = 0; ni < 4; ++ni)
                sq[ni] = s_qk[h * HD + ni * 16 + l16] * SQRT_DIM * ex;
#pragma unroll
            for (int mi = 0; mi < 8; ++mi)
#pragma unroll
                for (int r = 0; r < 4; ++r) {
                    float ss = 0.f;
#pragma unroll
                    for (int ni = 0; ni < 4; ++ni) ss += acc[mi][ni][r] * acc[mi][ni][r];
                    ss += __shfl_xor(ss, 1, 64);
                    ss += __shfl_xor(ss, 2, 64);
                    ss += __shfl_xor(ss, 4, 64);
                    ss += __shfl_xor(ss, 8, 64);
                    float inv = 1.f / fmaxf(sqrtf(ss), 1e-6f);
                    const int row = bm + wm * 128 + mi * 16 + quad * 4 + r;
                    const int bb = row >> 10, tok = row & 1023;
                    u16* o = dst + ((size_t)(bb * NHEADS + h) * SEQ + tok) * HD;
#pragma unroll
                    for (int ni = 0; ni < 4; ++ni)
                        o[ni * 16 + l16] = f2bf(acc[mi][ni][r] * sq[ni] * inv);
                }
        }
    } else {
        // =================== tail: 128x128 quarter-tiles (V heads 8..11) ====
        const int q = blk - 256;                 // 0..127
        const int bm = (q >> 1) * 128;
        const int bn = 2048 + (q & 1) * 128;
        const int wm4 = wave >> 1, wn2 = wave & 1; // 4M x 2N waves, 32x64 each
        const u16* Aq = A + (size_t)bm * K;
        const u16* Bq = B + (size_t)bn * K;

        f32x4 qa[2][4];
#pragma unroll
        for (int i = 0; i < 2; ++i)
#pragma unroll
            for (int j = 0; j < 4; ++j) qa[i][j] = (f32x4){0.f, 0.f, 0.f, 0.f};

        stg(Aq, As[0][0]);
        stg(Bq, Bs[0][0]);
        VM0;
        bar();
#pragma unroll 2
        for (int T = 0; T < NT; ++T) {
            const int db = T & 1;
            if (T + 1 < NT) {
                stg(Aq + (size_t)(T + 1) * 64, As[db ^ 1][0]);
                stg(Bq + (size_t)(T + 1) * 64, Bs[db ^ 1][0]);
            }
            const u16* Asl = As[db][0];
            const u16* Bsl = Bs[db][0];
            short8 af[2][2], bf[4][2];
#pragma unroll
            for (int mi = 0; mi < 2; ++mi) {
                const int r = wm4 * 32 + mi * 16 + l16;
#pragma unroll
                for (int kk = 0; kk < 2; ++kk)
                    af[mi][kk] = *(const short8*)&Asl[(r * 8 + ((kk * 4 + quad) ^ fx)) * 8];
            }
#pragma unroll
            for (int ni = 0; ni < 4; ++ni) {
                const int r = wn2 * 64 + ni * 16 + l16;
#pragma unroll
                for (int kk = 0; kk < 2; ++kk)
                    bf[ni][kk] = *(const short8*)&Bsl[(r * 8 + ((kk * 4 + quad) ^ fx)) * 8];
            }
            __builtin_amdgcn_s_setprio(1);
#pragma unroll
            for (int kk = 0; kk < 2; ++kk)
#pragma unroll
                for (int mi = 0; mi < 2; ++mi)
#pragma unroll
                    for (int ni = 0; ni < 4; ++ni)
                        qa[mi][ni] = MFMA16(af[mi][kk], bf[ni][kk], qa[mi][ni]);
            __builtin_amdgcn_s_setprio(0);
            VM0;
            bar();
        }
        // V epilogue (packed 8B stores), heads 8..11
        const int h = 8 + (q & 1) * 2 + wn2;
#pragma unroll
        for (int mi = 0; mi < 2; ++mi) {
            const int row = bm + wm4 * 32 + mi * 16 + quad * 4;
            const int bb = row >> 10, n0 = row & 1023;
#pragma unroll
            for (int ni = 0; ni < 4; ++ni) {
                const int dd = ni * 16 + l16;
                uint2 pk = make_uint2(rne_pack(qa[mi][ni][0], qa[mi][ni][1]),
                                      rne_pack(qa[mi][ni][2], qa[mi][ni][3]));
                *(uint2*)(Vt + (((size_t)(bb * NHEADS + h) * HD + dd) << 10) + n0) = pk;
            }
        }
    }
}

// ---------------------------------------------------------------------------
// bf16 MFMA GEMM: C = A[M,768] @ B[N,768]^T, fp32 accum. 128x128 tile,
// double-buffered BK=32 (one barrier/iter). Kept for the output projection
// (grid granularity: 384 blocks vs 96 at 256^2). EPI 0: fp32 C.
// ---------------------------------------------------------------------------
template <int EPI>
__global__ __launch_bounds__(256) void gemm_bf16(const u16* __restrict__ A,
                                                 const u16* __restrict__ B,
                                                 void* __restrict__ C, int N,
                                                 const float* __restrict__ s_qk,
                                                 u16* __restrict__ Qdst,
                                                 u16* __restrict__ Kdst,
                                                 int NX) {
    constexpr int K = NDIM;
    constexpr int NKT = K / 32; // 24 K-tiles
    __shared__ __align__(16) u16 As[2][4096]; // 8 KB per buffer
    __shared__ __align__(16) u16 Bs[2][4096];
    const int t = threadIdx.x;
    const int wave = t >> 6, lane = t & 63;
    const int quad = lane >> 4, l16 = lane & 15;
    const int wx = (wave & 1) * 64, wy = (wave >> 1) * 64;
    const int blk = blockIdx.x;
    const int xcd = blk & 7, local = blk >> 3;
    const int bm = (xcd * 8 + local / NX) * 128;
    const int bn = (local % NX) * 128;

    f32x4 acc[4][4];
#pragma unroll
    for (int i = 0; i < 4; ++i)
#pragma unroll
        for (int j = 0; j < 4; ++j) acc[i][j] = (f32x4){0.f, 0.f, 0.f, 0.f};

    const int srl = lane >> 2;
    const int skc = (lane & 3) ^ ((lane >> 3) & 3);
    auto stage = [&](int k0, int bsel) {
#pragma unroll
        for (int it = 0; it < 2; ++it) {
            const int cb = it * 256 + wave * 64;
            const int row = (cb >> 6) * 16 + srl;
            gl2lds16(A + (size_t)(bm + row) * K + k0 + skc * 8,
                     (char*)As[bsel] + cb * 16);
            gl2lds16(B + (size_t)(bn + row) * K + k0 + skc * 8,
                     (char*)Bs[bsel] + cb * 16);
        }
    };
    const int fxor = (l16 >> 1) & 3;

    stage(0, 0);
#pragma unroll
    for (int kt = 0; kt < NKT; ++kt) {
        __syncthreads();
        if (kt + 1 < NKT) stage((kt + 1) * 32, (kt + 1) & 1);
        const int b = kt & 1;
        short8 af[4], bfr[4];
#pragma unroll
        for (int i = 0; i < 4; ++i)
            af[i] = *(const short8*)&As[b][
                ((((wy >> 4) + i) * 64 + l16 * 4 + (quad ^ fxor)) * 8)];
#pragma unroll
        for (int j = 0; j < 4; ++j)
            bfr[j] = *(const short8*)&Bs[b][
                ((((wx >> 4) + j) * 64 + l16 * 4 + (quad ^ fxor)) * 8)];
#pragma unroll
        for (int i = 0; i < 4; ++i)
#pragma unroll
            for (int j = 0; j < 4; ++j) acc[i][j] = MFMA16(af[i], bfr[j], acc[i][j]);
    }

    if constexpr (EPI == 0) {
#pragma unroll
        for (int i = 0; i < 4; ++i)
#pragma unroll
            for (int j = 0; j < 4; ++j)
#pragma unroll
                for (int r = 0; r < 4; ++r) {
                    const int row = bm + wy + i * 16 + quad * 4 + r;
                    const int col = bn + wx + j * 16 + l16;
                    ((float*)C)[(size_t)row * N + col] = acc[i][j][r];
                }
    }
}

// ---------------------------------------------------------------------------
// MFMA flash attention, 32x32x16, no-max softmax. 256 threads = 4 waves;
// each wave owns 32 queries -> block = 128 queries; streams 64-key tiles.
// ---------------------------------------------------------------------------
__global__ __launch_bounds__(256) void attn_mfma(const u16* __restrict__ Qh,
                                                 const u16* __restrict__ Kh,
                                                 const u16* __restrict__ Vt,
                                                 u16* __restrict__ AO) {
    __shared__ __align__(16) u16 Ks[512 * 8];
    __shared__ __align__(16) u16 Vs[512 * 8];
    __shared__ __align__(16) u16 Ps[4 * 32 * 64]; // [wave][qrow][64], swizzled

    const int t = threadIdx.x;
    const int wave = t >> 6, lane = t & 63;
    const int l31 = lane & 31, half = lane >> 5;
    const int b = blockIdx.z, h = blockIdx.y, q0 = blockIdx.x * 128;
    const int bh = b * NHEADS + h;
    const u16* Kb = Kh + (size_t)bh * SEQ * HD;
    const u16* Vb = Vt + (size_t)bh * HD * SEQ;
    const int qb = q0 + wave * 32;
    const int pbase = wave * 2048 + l31 * 64;
    const int sw = (l31 & 15);

    short8 qf[4];
#pragma unroll
    for (int tt = 0; tt < 4; ++tt)
        qf[tt] = *(const short8*)(Qh + ((size_t)bh * SEQ + qb + l31) * HD +
                                  tt * 16 + half * 8);

    f32x16 o[2];
#pragma unroll
    for (int dt = 0; dt < 2; ++dt)
#pragma unroll
        for (int r = 0; r < 16; ++r) o[dt][r] = 0.f;
    float lp = 0.f;

    const int arl = lane >> 3;
    const int acc8 = (lane & 7) ^ arl;
    const int fx8 = l31 & 7;

    for (int j0 = 0; j0 < SEQ; j0 += 64) {
        __syncthreads();
#pragma unroll
        for (int it = 0; it < 2; ++it) {
            const int cb = it * 256 + wave * 64;
            const int r0 = (cb >> 6) * 8 + arl;
            gl2lds16(Kb + (size_t)(j0 + r0) * HD + acc8 * 8, (char*)Ks + cb * 16);
            gl2lds16(Vb + (size_t)r0 * SEQ + j0 + acc8 * 8, (char*)Vs + cb * 16);
        }
        asm volatile("s_waitcnt vmcnt(0)" ::: "memory");
        __syncthreads();

        // ---- S^T phase: 64 keys x 32 queries ----
#pragma unroll
        for (int kt = 0; kt < 2; ++kt) {
            f32x16 sa;
#pragma unroll
            for (int r = 0; r < 16; ++r) sa[r] = 0.f;
#pragma unroll
            for (int tt = 0; tt < 4; ++tt) {
                short8 kf = *(const short8*)&Ks[
                    (((kt * 4 + (l31 >> 3)) * 64) + fx8 * 8 +
                     ((2 * tt + half) ^ fx8)) * 8];
                sa = MFMA32(kf, qf[tt], sa);
            }
#pragma unroll
            for (int rg = 0; rg < 4; ++rg) {
                float p0 = EXP2(sa[rg * 4 + 0]);
                float p1 = EXP2(sa[rg * 4 + 1]);
                float p2 = EXP2(sa[rg * 4 + 2]);
                float p3 = EXP2(sa[rg * 4 + 3]);
                lp += (p0 + p1) + (p2 + p3);
                uint2 pk = make_uint2(rne_pack(p0, p1), rne_pack(p2, p3));
                const int u = kt * 8 + rg * 2 + half;
                *(uint2*)&Ps[pbase + (u ^ sw) * 4] = pk;
            }
        }

        // ---- PV phase: O^T += V^T @ P ----
#pragma unroll
        for (int k2 = 0; k2 < 4; ++k2) {
            const int u0 = k2 * 4 + half * 2;
            bf16x4 lo = *(const bf16x4*)&Ps[pbase + ((u0 + 0) ^ sw) * 4];
            bf16x4 hi = *(const bf16x4*)&Ps[pbase + ((u0 + 1) ^ sw) * 4];
            short8 pf = __builtin_shufflevector(lo, hi, 0, 1, 2, 3, 4, 5, 6, 7);
#pragma unroll
            for (int dt = 0; dt < 2; ++dt) {
                short8 vf = *(const short8*)&Vs[
                    (((dt * 4 + (l31 >> 3)) * 64) + fx8 * 8 +
                     ((2 * k2 + half) ^ fx8)) * 8];
                o[dt] = MFMA32(vf, pf, o[dt]);
            }
        }
    }

    const float invl = 1.f / (lp + __shfl_xor(lp, 32, 64));
    u16* ob = AO + (size_t)(b * SEQ + qb + l31) * NDIM + h * HD;
#pragma unroll
    for (int dt = 0; dt < 2; ++dt)
#pragma unroll
        for (int rg = 0; rg < 4; ++rg) {
            bf16x4 ok = {(short)f2bf(o[dt][rg * 4 + 0] * invl),
                         (short)f2bf(o[dt][rg * 4 + 1] * invl),
                         (short)f2bf(o[dt][rg * 4 + 2] * invl),
                         (short)f2bf(o[dt][rg * 4 + 3] * invl)};
            *(bf16x4*)(ob + dt * 32 + rg * 8 + half * 4) = ok;
        }
}

// ---------------------------------------------------------------------------
extern "C" void kernel_launch(void* const* d_in, const int* in_sizes, int n_in,
                              void* d_out, int out_size, void* d_ws, size_t ws_size,
                              hipStream_t stream) {
    const float* x    = (const float*)d_in[0];
    const float* Wq   = (const float*)d_in[1];
    const float* Wk   = (const float*)d_in[2];
    const float* Wv   = (const float*)d_in[3];
    const float* Wo   = (const float*)d_in[4];
    const float* s_qk = (const float*)d_in[5];
    float* out = (float*)d_out;

    char* w = (char*)d_ws;
    const size_t TE = (size_t)MROWS * NDIM;
    u16* xb   = (u16*)w;                    w += TE * 2;
    u16* Wqkv = (u16*)w;                    w += (size_t)3 * NDIM * NDIM * 2;
    u16* Wob  = (u16*)w;                    w += (size_t)NDIM * NDIM * 2;
    u16* Qh   = (u16*)w;                    w += TE * 2;
    u16* Kh   = (u16*)w;                    w += TE * 2;
    u16* Vt   = (u16*)w;                    w += TE * 2;
    u16* ao   = (u16*)w;

    castall<<<6144 + 4 * 576, 256, 0, stream>>>(x, Wq, Wk, Wv, Wo, xb, Wqkv, Wob);

    // Fused QKV projection: 256 full 256^2 tiles (one round) + 128 quarter
    // tiles that fill the scheduling tail.
    gemm256_qkv<<<384, 512, 0, stream>>>(xb, Wqkv, Vt, s_qk, Qh, Kh);

    attn_mfma<<<dim3(SEQ / 128, NHEADS, BATCH), 256, 0, stream>>>(Qh, Kh, Vt, ao);

    // Output projection: NX = 768/128 = 6
    gemm_bf16<0><<<6 * 64, 256, 0, stream>>>(
        ao, Wob, out, NDIM, nullptr, nullptr, nullptr, 6);
}

// Round 3
// 190.328 us; speedup vs baseline: 1.0681x; 1.0108x over previous
//
#include <hip/hip_runtime.h>
#include <hip/hip_bf16.h>
#include <math.h>

#define NDIM 768
#define NHEADS 12
#define HD 64
#define SEQ 1024
#define BATCH 8
#define MROWS (BATCH * SEQ)          // 8192
#define SQRT_DIM 27.712812921102035f // 1/SCALE_PARAM_INIT
#define LOG2E 1.4426950408889634f

typedef unsigned short u16;
typedef unsigned int u32;
typedef __attribute__((ext_vector_type(8))) short short8;   // 8 bf16 = 4 VGPRs
typedef __attribute__((ext_vector_type(4))) short bf16x4;   // 4 bf16 = 2 VGPRs
typedef __attribute__((ext_vector_type(4))) float f32x4;
typedef __attribute__((ext_vector_type(16))) float f32x16;
typedef __attribute__((ext_vector_type(2))) u32 u32x2;
typedef __attribute__((ext_vector_type(4))) u32 u32x4;

#define MFMA16(a, b, c) __builtin_amdgcn_mfma_f32_16x16x32_bf16(a, b, c, 0, 0, 0)
#define MFMA32(a, b, c) __builtin_amdgcn_mfma_f32_32x32x16_bf16(a, b, c, 0, 0, 0)

#if __has_builtin(__builtin_amdgcn_exp2f)
#define EXP2(x) __builtin_amdgcn_exp2f(x)
#else
#define EXP2(x) exp2f(x)
#endif

__device__ inline u16 f2bf(float f) {
    __hip_bfloat16 h = __float2bfloat16(f);
    return *reinterpret_cast<u16*>(&h);
}

// RNE round a,b to bf16 and pack into one u32 (a = low half). No NaN check —
// callers guarantee finite inputs.
__device__ inline u32 rne_pack(float a, float b) {
    u32 ua = __builtin_bit_cast(u32, a), ub = __builtin_bit_cast(u32, b);
    ua = (ua + 0x7fffu + ((ua >> 16) & 1u)) >> 16;
    ub = (ub + 0x7fffu + ((ub >> 16) & 1u)) >> 16;
    return (ub << 16) | ua;
}

// async 16B global->LDS. LDS dest is wave-uniform base; HW adds lane*16.
__device__ inline void gl2lds16(const void* g, void* l) {
    __builtin_amdgcn_global_load_lds((const __attribute__((address_space(1))) void*)g,
                                     (__attribute__((address_space(3))) void*)l, 16, 0, 0);
}

// compiler-fenced raw barrier (NO vmcnt drain — that is the whole point)
__device__ inline void bar() {
    asm volatile("" ::: "memory");
    __builtin_amdgcn_s_barrier();
    asm volatile("" ::: "memory");
}
#define LGKM0 asm volatile("s_waitcnt lgkmcnt(0)" ::: "memory")
#define VM0   asm volatile("s_waitcnt vmcnt(0)" ::: "memory")

// half-swap: x[i] = i<32 ? a[i] : b[i-32]; y[i] = i<32 ? a[i+32] : b[i].
// One v_permlane32_swap_b32 yields both outputs (T12); shfl fallback.
__device__ inline void plswap(u32 a, u32 b, int half, u32& x, u32& y) {
#if __has_builtin(__builtin_amdgcn_permlane32_swap)
    u32x2 r = __builtin_amdgcn_permlane32_swap(a, b, false, false);
    x = r[0]; y = r[1];
#else
    u32 oa = __shfl_xor(a, 32, 64), ob = __shfl_xor(b, 32, 64);
    x = half ? ob : a;
    y = half ? b : oa;
#endif
}

// ---------------------------------------------------------------------------
// One fused cast kernel: x (6144 blocks) + Wq/Wk/Wv -> Wqkv, Wo -> Wob.
// ---------------------------------------------------------------------------
__global__ __launch_bounds__(256) void castall(const float* __restrict__ x,
                                               const float* __restrict__ Wq,
                                               const float* __restrict__ Wk,
                                               const float* __restrict__ Wv,
                                               const float* __restrict__ Wo,
                                               u16* __restrict__ xb,
                                               u16* __restrict__ Wqkv,
                                               u16* __restrict__ Wob) {
    const int WB = (NDIM * NDIM) / 1024; // 576 blocks per weight
    int blk = blockIdx.x;
    const float* s;
    u16* d;
    int base;
    if (blk < 6144) {
        s = x; d = xb; base = blk * 1024;
    } else {
        int wsel = (blk - 6144) / WB, r = (blk - 6144) % WB;
        base = r * 1024;
        if (wsel == 0)      { s = Wq; d = Wqkv; }
        else if (wsel == 1) { s = Wk; d = Wqkv + NDIM * NDIM; }
        else if (wsel == 2) { s = Wv; d = Wqkv + 2 * NDIM * NDIM; }
        else                { s = Wo; d = Wob; }
    }
    int i = base + threadIdx.x * 4;
    float4 v = *(const float4*)(s + i);
    uint2 o = make_uint2(rne_pack(v.x, v.y), rne_pack(v.z, v.w));
    *(uint2*)(d + i) = o;
}

// ---------------------------------------------------------------------------
// 256x256 / BK=64 / 8-wave 8-phase GEMM (T3+T4+T5 template) for the fused
// QKV projection: C = A[8192,768] @ B[2304,768]^T with fused cosine-norm
// (Q/K) and transposed-V epilogue.
//
// Scheduling: 288 output tiles don't fit 256 CUs at 1 blk/CU, so grid = 384:
//   blk 0..255  : full 256^2 tiles over N-tiles 0..7 (exactly one round)
//   blk 256..383: 128x128 quarter-tiles over the last N-strip (V heads 8..11)
// ---------------------------------------------------------------------------
__global__ __launch_bounds__(512, 2) void gemm256_qkv(const u16* __restrict__ A,
                                                      const u16* __restrict__ B,
                                                      u16* __restrict__ Vt,
                                                      const float* __restrict__ s_qk,
                                                      u16* __restrict__ Qdst,
                                                      u16* __restrict__ Kdst) {
    constexpr int K = NDIM;     // 768
    constexpr int NT = K / 64;  // 12 K-tiles
    __shared__ __align__(16) u16 As[2][2][128 * 64]; // [dbuf][half][r*8+slot]
    __shared__ __align__(16) u16 Bs[2][2][128 * 64];

    const int t = threadIdx.x;
    const int wave = t >> 6, lane = t & 63;
    const int quad = lane >> 4, l16 = lane & 15;
    const int fx = l16 & 7;                  // fragment-read XOR key
    const int blk = blockIdx.x;

    // half-tile stage: 128 rows x 64 k = 16 KB = 512 thr x 2 x 16B.
    const int srow = lane >> 3;
    const int schk = (lane & 7) ^ srow;
    auto stg = [&](const u16* src, u16* dst) {
#pragma unroll
        for (int it = 0; it < 2; ++it) {
            const int cb = it * 512 + wave * 64; // slot base, wave-uniform
            const int r = (cb >> 3) + srow;      // row 0..127
            gl2lds16(src + (size_t)r * K + schk * 8, (char*)dst + cb * 16);
        }
    };

    if (blk < 256) {
        // =================== full 256^2 8-phase path ===================
        const int wm = wave >> 2, wn = wave & 3; // 2 x 4 wave grid, 128x64 each
        const int xcd = blk & 7, local = blk >> 3;            // 0..31
        const int bm = xcd * 1024 + (local >> 3) * 256;       // 4 M-tiles/XCD
        const int bn = (local & 7) * 256;                     // N-tiles 0..7

        f32x4 acc[8][4];
#pragma unroll
        for (int i = 0; i < 8; ++i)
#pragma unroll
            for (int j = 0; j < 4; ++j) acc[i][j] = (f32x4){0.f, 0.f, 0.f, 0.f};

        const u16* Ag = A + (size_t)bm * K;
        const u16* Bg = B + (size_t)bn * K;

        // prologue: tile0 {A,B} + tile1 {B}; wait tile0 (12 issued, 4 may fly)
        stg(Ag,                        As[0][0]);
        stg(Ag + (size_t)128 * K,      As[0][1]);
        stg(Bg,                        Bs[0][0]);
        stg(Bg + (size_t)128 * K,      Bs[0][1]);
        stg(Bg + 64,                   Bs[1][0]);
        stg(Bg + (size_t)128 * K + 64, Bs[1][1]);
        asm volatile("s_waitcnt vmcnt(4)" ::: "memory");
        bar();

        short8 a[4][2], b0[2][2], b1[2][2];
        const int rb0 = (wn & 1) * 64; // this wave's B-row base within its half

#pragma unroll 2
        for (int T = 0; T < NT; ++T) {
            const int db = T & 1;
            u16* Asl = As[db][wm];
            u16* Bsl = Bs[db][wn >> 1];
            const u16* An = Ag + (size_t)(T + 1) * 64;
            const u16* Bn = Bg + (size_t)(T + 2) * 64;

            // ---- P0: read A[mi0-3] + B[ni0-1]; stage A(T+1)h0; MFMA Q(0,0) ----
#pragma unroll
            for (int mi = 0; mi < 4; ++mi) {
                const int r = mi * 16 + l16;
#pragma unroll
                for (int kk = 0; kk < 2; ++kk)
                    a[mi][kk] = *(const short8*)&Asl[(r * 8 + ((kk * 4 + quad) ^ fx)) * 8];
            }
#pragma unroll
            for (int ni = 0; ni < 2; ++ni) {
                const int r = rb0 + ni * 16 + l16;
#pragma unroll
                for (int kk = 0; kk < 2; ++kk)
                    b0[ni][kk] = *(const short8*)&Bsl[(r * 8 + ((kk * 4 + quad) ^ fx)) * 8];
            }
            if (T + 1 < NT) stg(An, As[db ^ 1][0]);
            bar();
            LGKM0;
            __builtin_amdgcn_s_setprio(1);
#pragma unroll
            for (int kk = 0; kk < 2; ++kk)
#pragma unroll
                for (int mi = 0; mi < 4; ++mi)
#pragma unroll
                    for (int ni = 0; ni < 2; ++ni)
                        acc[mi][ni] = MFMA16(a[mi][kk], b0[ni][kk], acc[mi][ni]);
            __builtin_amdgcn_s_setprio(0);
            bar();

            // ---- P1: read B[ni2-3]; stage A(T+1)h1; MFMA Q(0,1) ----
#pragma unroll
            for (int ni = 0; ni < 2; ++ni) {
                const int r = rb0 + (ni + 2) * 16 + l16;
#pragma unroll
                for (int kk = 0; kk < 2; ++kk)
                    b1[ni][kk] = *(const short8*)&Bsl[(r * 8 + ((kk * 4 + quad) ^ fx)) * 8];
            }
            if (T + 1 < NT) stg(An + (size_t)128 * K, As[db ^ 1][1]);
            bar();
            LGKM0;
            __builtin_amdgcn_s_setprio(1);
#pragma unroll
            for (int kk = 0; kk < 2; ++kk)
#pragma unroll
                for (int mi = 0; mi < 4; ++mi)
#pragma unroll
                    for (int ni = 0; ni < 2; ++ni)
                        acc[mi][ni + 2] = MFMA16(a[mi][kk], b1[ni][kk], acc[mi][ni + 2]);
            __builtin_amdgcn_s_setprio(0);
            bar();

            // ---- P2: read A[mi4-7]; stage B(T+2)h0; MFMA Q(1,1) ----
#pragma unroll
            for (int mi = 0; mi < 4; ++mi) {
                const int r = (mi + 4) * 16 + l16;
#pragma unroll
                for (int kk = 0; kk < 2; ++kk)
                    a[mi][kk] = *(const short8*)&Asl[(r * 8 + ((kk * 4 + quad) ^ fx)) * 8];
            }
            if (T + 2 < NT) stg(Bn, Bs[db][0]);
            bar();
            LGKM0;
            __builtin_amdgcn_s_setprio(1);
#pragma unroll
            for (int kk = 0; kk < 2; ++kk)
#pragma unroll
                for (int mi = 0; mi < 4; ++mi)
#pragma unroll
                    for (int ni = 0; ni < 2; ++ni)
                        acc[mi + 4][ni + 2] = MFMA16(a[mi][kk], b1[ni][kk], acc[mi + 4][ni + 2]);
            __builtin_amdgcn_s_setprio(0);
            bar();

            // ---- P3: stage B(T+2)h1; MFMA Q(1,0); counted vmcnt; bar ----
            if (T + 2 < NT) stg(Bn + (size_t)128 * K, Bs[db][1]);
            bar();
            __builtin_amdgcn_s_setprio(1);
#pragma unroll
            for (int kk = 0; kk < 2; ++kk)
#pragma unroll
                for (int mi = 0; mi < 4; ++mi)
#pragma unroll
                    for (int ni = 0; ni < 2; ++ni)
                        acc[mi + 4][ni] = MFMA16(a[mi][kk], b0[ni][kk], acc[mi + 4][ni]);
            __builtin_amdgcn_s_setprio(0);
            if (T + 2 < NT) {
                asm volatile("s_waitcnt vmcnt(4)" ::: "memory"); // tile T+1 resident
            } else {
                VM0; // drains A(NT-1) too (last two iters)
            }
            bar();
        }

        // ---- fused QKV epilogue (wave's 64 cols = exactly one head-group) ----
        const int cg = (bn + wn * 64) >> 6; // 0..31 here
        if (cg >= 2 * NHEADS) {
            // V path: transposed bf16 write, 4 consecutive tokens packed -> 8B
            const int h = cg - 2 * NHEADS;
#pragma unroll
            for (int mi = 0; mi < 8; ++mi) {
                const int row = bm + wm * 128 + mi * 16 + quad * 4; // token base
                const int bb = row >> 10, n0 = row & 1023;
#pragma unroll
                for (int ni = 0; ni < 4; ++ni) {
                    const int dd = ni * 16 + l16;
                    uint2 pk = make_uint2(rne_pack(acc[mi][ni][0], acc[mi][ni][1]),
                                          rne_pack(acc[mi][ni][2], acc[mi][ni][3]));
                    *(uint2*)(Vt + (((size_t)(bb * NHEADS + h) * HD + dd) << 10) + n0) = pk;
                }
            }
        } else {
            const bool isq = cg < NHEADS;
            const int h = isq ? cg : cg - NHEADS;
            u16* dst = isq ? Qdst : Kdst;
            const float ex = isq ? 8.f * LOG2E : 1.f;
            float sq[4];
#pragma unroll
            for (int ni = 0; ni < 4; ++ni)
                sq[ni] = s_qk[h * HD + ni * 16 + l16] * SQRT_DIM * ex;
#pragma unroll
            for (int mi = 0; mi < 8; ++mi)
#pragma unroll
                for (int r = 0; r < 4; ++r) {
                    float ss = 0.f;
#pragma unroll
                    for (int ni = 0; ni < 4; ++ni) ss += acc[mi][ni][r] * acc[mi][ni][r];
                    ss += __shfl_xor(ss, 1, 64);
                    ss += __shfl_xor(ss, 2, 64);
                    ss += __shfl_xor(ss, 4, 64);
                    ss += __shfl_xor(ss, 8, 64);
                    float inv = 1.f / fmaxf(sqrtf(ss), 1e-6f);
                    const int row = bm + wm * 128 + mi * 16 + quad * 4 + r;
                    const int bb = row >> 10, tok = row & 1023;
                    u16* o = dst + ((size_t)(bb * NHEADS + h) * SEQ + tok) * HD;
#pragma unroll
                    for (int ni = 0; ni < 4; ++ni)
                        o[ni * 16 + l16] = f2bf(acc[mi][ni][r] * sq[ni] * inv);
                }
        }
    } else {
        // =================== tail: 128x128 quarter-tiles (V heads 8..11) ====
        const int q = blk - 256;                 // 0..127
        const int bm = (q >> 1) * 128;
        const int bn = 2048 + (q & 1) * 128;
        const int wm4 = wave >> 1, wn2 = wave & 1; // 4M x 2N waves, 32x64 each
        const u16* Aq = A + (size_t)bm * K;
        const u16* Bq = B + (size_t)bn * K;

        f32x4 qa[2][4];
#pragma unroll
        for (int i = 0; i < 2; ++i)
#pragma unroll
            for (int j = 0; j < 4; ++j) qa[i][j] = (f32x4){0.f, 0.f, 0.f, 0.f};

        stg(Aq, As[0][0]);
        stg(Bq, Bs[0][0]);
        VM0;
        bar();
#pragma unroll 2
        for (int T = 0; T < NT; ++T) {
            const int db = T & 1;
            if (T + 1 < NT) {
                stg(Aq + (size_t)(T + 1) * 64, As[db ^ 1][0]);
                stg(Bq + (size_t)(T + 1) * 64, Bs[db ^ 1][0]);
            }
            const u16* Asl = As[db][0];
            const u16* Bsl = Bs[db][0];
            short8 af[2][2], bf[4][2];
#pragma unroll
            for (int mi = 0; mi < 2; ++mi) {
                const int r = wm4 * 32 + mi * 16 + l16;
#pragma unroll
                for (int kk = 0; kk < 2; ++kk)
                    af[mi][kk] = *(const short8*)&Asl[(r * 8 + ((kk * 4 + quad) ^ fx)) * 8];
            }
#pragma unroll
            for (int ni = 0; ni < 4; ++ni) {
                const int r = wn2 * 64 + ni * 16 + l16;
#pragma unroll
                for (int kk = 0; kk < 2; ++kk)
                    bf[ni][kk] = *(const short8*)&Bsl[(r * 8 + ((kk * 4 + quad) ^ fx)) * 8];
            }
            __builtin_amdgcn_s_setprio(1);
#pragma unroll
            for (int kk = 0; kk < 2; ++kk)
#pragma unroll
                for (int mi = 0; mi < 2; ++mi)
#pragma unroll
                    for (int ni = 0; ni < 4; ++ni)
                        qa[mi][ni] = MFMA16(af[mi][kk], bf[ni][kk], qa[mi][ni]);
            __builtin_amdgcn_s_setprio(0);
            VM0;
            bar();
        }
        // V epilogue (packed 8B stores), heads 8..11
        const int h = 8 + (q & 1) * 2 + wn2;
#pragma unroll
        for (int mi = 0; mi < 2; ++mi) {
            const int row = bm + wm4 * 32 + mi * 16 + quad * 4;
            const int bb = row >> 10, n0 = row & 1023;
#pragma unroll
            for (int ni = 0; ni < 4; ++ni) {
                const int dd = ni * 16 + l16;
                uint2 pk = make_uint2(rne_pack(qa[mi][ni][0], qa[mi][ni][1]),
                                      rne_pack(qa[mi][ni][2], qa[mi][ni][3]));
                *(uint2*)(Vt + (((size_t)(bb * NHEADS + h) * HD + dd) << 10) + n0) = pk;
            }
        }
    }
}

// ---------------------------------------------------------------------------
// bf16 MFMA GEMM: C = A[M,768] @ B[N,768]^T, fp32 accum. 128x128 tile,
// double-buffered BK=32 (one barrier/iter). Kept for the output projection.
// ---------------------------------------------------------------------------
template <int EPI>
__global__ __launch_bounds__(256) void gemm_bf16(const u16* __restrict__ A,
                                                 const u16* __restrict__ B,
                                                 void* __restrict__ C, int N,
                                                 const float* __restrict__ s_qk,
                                                 u16* __restrict__ Qdst,
                                                 u16* __restrict__ Kdst,
                                                 int NX) {
    constexpr int K = NDIM;
    constexpr int NKT = K / 32; // 24 K-tiles
    __shared__ __align__(16) u16 As[2][4096]; // 8 KB per buffer
    __shared__ __align__(16) u16 Bs[2][4096];
    const int t = threadIdx.x;
    const int wave = t >> 6, lane = t & 63;
    const int quad = lane >> 4, l16 = lane & 15;
    const int wx = (wave & 1) * 64, wy = (wave >> 1) * 64;
    const int blk = blockIdx.x;
    const int xcd = blk & 7, local = blk >> 3;
    const int bm = (xcd * 8 + local / NX) * 128;
    const int bn = (local % NX) * 128;

    f32x4 acc[4][4];
#pragma unroll
    for (int i = 0; i < 4; ++i)
#pragma unroll
        for (int j = 0; j < 4; ++j) acc[i][j] = (f32x4){0.f, 0.f, 0.f, 0.f};

    const int srl = lane >> 2;
    const int skc = (lane & 3) ^ ((lane >> 3) & 3);
    auto stage = [&](int k0, int bsel) {
#pragma unroll
        for (int it = 0; it < 2; ++it) {
            const int cb = it * 256 + wave * 64;
            const int row = (cb >> 6) * 16 + srl;
            gl2lds16(A + (size_t)(bm + row) * K + k0 + skc * 8,
                     (char*)As[bsel] + cb * 16);
            gl2lds16(B + (size_t)(bn + row) * K + k0 + skc * 8,
                     (char*)Bs[bsel] + cb * 16);
        }
    };
    const int fxor = (l16 >> 1) & 3;

    stage(0, 0);
#pragma unroll
    for (int kt = 0; kt < NKT; ++kt) {
        __syncthreads();
        if (kt + 1 < NKT) stage((kt + 1) * 32, (kt + 1) & 1);
        const int b = kt & 1;
        short8 af[4], bfr[4];
#pragma unroll
        for (int i = 0; i < 4; ++i)
            af[i] = *(const short8*)&As[b][
                ((((wy >> 4) + i) * 64 + l16 * 4 + (quad ^ fxor)) * 8)];
#pragma unroll
        for (int j = 0; j < 4; ++j)
            bfr[j] = *(const short8*)&Bs[b][
                ((((wx >> 4) + j) * 64 + l16 * 4 + (quad ^ fxor)) * 8)];
#pragma unroll
        for (int i = 0; i < 4; ++i)
#pragma unroll
            for (int j = 0; j < 4; ++j) acc[i][j] = MFMA16(af[i], bfr[j], acc[i][j]);
    }

    if constexpr (EPI == 0) {
#pragma unroll
        for (int i = 0; i < 4; ++i)
#pragma unroll
            for (int j = 0; j < 4; ++j)
#pragma unroll
                for (int r = 0; r < 4; ++r) {
                    const int row = bm + wy + i * 16 + quad * 4 + r;
                    const int col = bn + wx + j * 16 + l16;
                    ((float*)C)[(size_t)row * N + col] = acc[i][j][r];
                }
    }
}

// ---------------------------------------------------------------------------
// MFMA flash attention, 32x32x16, no-max softmax. 256 threads = 4 waves;
// each wave owns 32 queries -> block = 128 queries; streams 64-key tiles.
//
// r3 restructure:
//  - P in registers: S^T accumulator -> bf16 packs -> v_permlane32_swap
//    half-exchange -> PV B-fragments directly (no Ps LDS buffer, no
//    round-trip, removes the 3.9M bank-conflict source).
//  - K/V double-buffered; stage(jt+1) issued right after the single
//    barrier so HBM/L2 latency hides under S+PV compute (T14/T3-lite).
//  - 1D XCD-grouped grid: all 8 q-blocks of one (b,h) on one XCD so K/V
//    (3 MB per 12 heads) lives in that XCD's L2 (cuts HBM re-fetch).
// ---------------------------------------------------------------------------
__global__ __launch_bounds__(256) void attn_mfma(const u16* __restrict__ Qh,
                                                 const u16* __restrict__ Kh,
                                                 const u16* __restrict__ Vt,
                                                 u16* __restrict__ AO) {
    __shared__ __align__(16) u16 Ks[2][512 * 8];
    __shared__ __align__(16) u16 Vs[2][512 * 8];

    const int t = threadIdx.x;
    const int wave = t >> 6, lane = t & 63;
    const int l31 = lane & 31, half = lane >> 5;

    // XCD-grouped decode: bid&7 -> XCD slot; 12 (b,h) per XCD; 8 q-blocks each
    const int bid = blockIdx.x;
    const int xcd = bid & 7, idx = bid >> 3;      // idx 0..95
    const int bh = xcd * 12 + (idx % 12);
    const int q0 = (idx / 12) * 128;
    const int b = bh / NHEADS, h = bh - b * NHEADS;

    const u16* Kb = Kh + (size_t)bh * SEQ * HD;
    const u16* Vb = Vt + (size_t)bh * HD * SEQ;
    const int qb = q0 + wave * 32;

    // Q fragments (B-operand: n = query = l31, k = tt*16 + half*8 + j)
    short8 qf[4];
#pragma unroll
    for (int tt = 0; tt < 4; ++tt)
        qf[tt] = *(const short8*)(Qh + ((size_t)bh * SEQ + qb + l31) * HD +
                                  tt * 16 + half * 8);

    f32x16 o[2]; // [d-tile]
#pragma unroll
    for (int dt = 0; dt < 2; ++dt)
#pragma unroll
        for (int r = 0; r < 16; ++r) o[dt][r] = 0.f;
    float lp = 0.f;

    // staging lane->global mapping (inverse of slot swizzle)
    const int arl = lane >> 3;            // row within 8-row span
    const int acc8 = (lane & 7) ^ arl;    // chunk 0..7
    // fragment-read bank spread piece
    const int fx8 = l31 & 7;

    auto stage = [&](int j0, int db) {
#pragma unroll
        for (int it = 0; it < 2; ++it) {
            const int cb = it * 256 + wave * 64; // span base, wave-uniform
            const int r0 = (cb >> 6) * 8 + arl;  // row 0..63
            gl2lds16(Kb + (size_t)(j0 + r0) * HD + acc8 * 8,
                     (char*)Ks[db] + cb * 16);
            gl2lds16(Vb + (size_t)r0 * SEQ + j0 + acc8 * 8,
                     (char*)Vs[db] + cb * 16);
        }
    };

    stage(0, 0);
    for (int jt = 0; jt < SEQ / 64; ++jt) {
        const int db = jt & 1;
        VM0;   // own tile-jt loads done (issued one full compute phase ago)
        bar(); // all waves' loads landed; all waves done reading buf db^1
        if (jt + 1 < SEQ / 64) stage((jt + 1) * 64, db ^ 1);
        const u16* Ksl = Ks[db];
        const u16* Vsl = Vs[db];

#pragma unroll
        for (int kt = 0; kt < 2; ++kt) {
            // ---- S^T: 32 keys x 32 queries ----
            f32x16 sa;
#pragma unroll
            for (int r = 0; r < 16; ++r) sa[r] = 0.f;
#pragma unroll
            for (int tt = 0; tt < 4; ++tt) {
                short8 kf = *(const short8*)&Ksl[
                    (((kt * 4 + (l31 >> 3)) * 64) + fx8 * 8 +
                     ((2 * tt + half) ^ fx8)) * 8];
                sa = MFMA32(kf, qf[tt], sa);
            }
            // ---- softmax numerator in-register ----
            float p[16];
#pragma unroll
            for (int r = 0; r < 16; ++r) p[r] = EXP2(sa[r]);
#pragma unroll
            for (int rg = 0; rg < 4; ++rg)
                lp += (p[rg * 4] + p[rg * 4 + 1]) + (p[rg * 4 + 2] + p[rg * 4 + 3]);
            u32 q[8];
#pragma unroll
            for (int i = 0; i < 8; ++i) q[i] = rne_pack(p[2 * i], p[2 * i + 1]);
            // half-exchange: acc layout (keys 4h..) -> B-frag layout (keys 8h..)
            u32 d0, d1, d2, d3, e0, e1, e2, e3;
            plswap(q[0], q[2], half, d0, d2);
            plswap(q[1], q[3], half, d1, d3);
            plswap(q[4], q[6], half, e0, e2);
            plswap(q[5], q[7], half, e1, e3);
            u32x4 f0v = {d0, d1, d2, d3};
            u32x4 f1v = {e0, e1, e2, e3};
            short8 pf0 = __builtin_bit_cast(short8, f0v);
            short8 pf1 = __builtin_bit_cast(short8, f1v);
            // ---- PV: O^T += V^T @ P for the two 16-key slices of this kt ----
#pragma unroll
            for (int s = 0; s < 2; ++s) {
                short8 pf = s ? pf1 : pf0;
                const int c = kt * 4 + s * 2 + half; // = 2*k2 + half
#pragma unroll
                for (int dt = 0; dt < 2; ++dt) {
                    short8 vf = *(const short8*)&Vsl[
                        (((dt * 4 + (l31 >> 3)) * 64) + fx8 * 8 + (c ^ fx8)) * 8];
                    o[dt] = MFMA32(vf, pf, o[dt]);
                }
            }
        }
    }

    // final l reduction (halves hold disjoint key subsets) and output
    const float invl = 1.f / (lp + __shfl_xor(lp, 32, 64));
    u16* ob = AO + (size_t)(b * SEQ + qb + l31) * NDIM + h * HD;
#pragma unroll
    for (int dt = 0; dt < 2; ++dt)
#pragma unroll
        for (int rg = 0; rg < 4; ++rg) {
            bf16x4 ok = {(short)f2bf(o[dt][rg * 4 + 0] * invl),
                         (short)f2bf(o[dt][rg * 4 + 1] * invl),
                         (short)f2bf(o[dt][rg * 4 + 2] * invl),
                         (short)f2bf(o[dt][rg * 4 + 3] * invl)};
            *(bf16x4*)(ob + dt * 32 + rg * 8 + half * 4) = ok;
        }
}

// ---------------------------------------------------------------------------
extern "C" void kernel_launch(void* const* d_in, const int* in_sizes, int n_in,
                              void* d_out, int out_size, void* d_ws, size_t ws_size,
                              hipStream_t stream) {
    const float* x    = (const float*)d_in[0];
    const float* Wq   = (const float*)d_in[1];
    const float* Wk   = (const float*)d_in[2];
    const float* Wv   = (const float*)d_in[3];
    const float* Wo   = (const float*)d_in[4];
    const float* s_qk = (const float*)d_in[5];
    float* out = (float*)d_out;

    char* w = (char*)d_ws;
    const size_t TE = (size_t)MROWS * NDIM;
    u16* xb   = (u16*)w;                    w += TE * 2;
    u16* Wqkv = (u16*)w;                    w += (size_t)3 * NDIM * NDIM * 2;
    u16* Wob  = (u16*)w;                    w += (size_t)NDIM * NDIM * 2;
    u16* Qh   = (u16*)w;                    w += TE * 2;
    u16* Kh   = (u16*)w;                    w += TE * 2;
    u16* Vt   = (u16*)w;                    w += TE * 2;
    u16* ao   = (u16*)w;

    castall<<<6144 + 4 * 576, 256, 0, stream>>>(x, Wq, Wk, Wv, Wo, xb, Wqkv, Wob);

    // Fused QKV projection: 256 full 256^2 tiles (one round) + 128 quarter
    // tiles that fill the scheduling tail.
    gemm256_qkv<<<384, 512, 0, stream>>>(xb, Wqkv, Vt, s_qk, Qh, Kh);

    // Flash attention, XCD-grouped 1D grid (768 = 8 xcd x 12 bh x 8 qblk)
    attn_mfma<<<768, 256, 0, stream>>>(Qh, Kh, Vt, ao);

    // Output projection: NX = 768/128 = 6
    gemm_bf16<0><<<6 * 64, 256, 0, stream>>>(
        ao, Wob, out, NDIM, nullptr, nullptr, nullptr, 6);
}

// Round 4
// 179.225 us; speedup vs baseline: 1.1342x; 1.0619x over previous
//
#include <hip/hip_runtime.h>
#include <hip/hip_bf16.h>
#include <math.h>

#define NDIM 768
#define NHEADS 12
#define HD 64
#define SEQ 1024
#define BATCH 8
#define MROWS (BATCH * SEQ)          // 8192
#define SQRT_DIM 27.712812921102035f // 1/SCALE_PARAM_INIT
#define LOG2E 1.4426950408889634f

typedef unsigned short u16;
typedef unsigned int u32;
typedef __attribute__((ext_vector_type(8))) short short8;   // 8 bf16 = 4 VGPRs
typedef __attribute__((ext_vector_type(4))) short bf16x4;   // 4 bf16 = 2 VGPRs
typedef __attribute__((ext_vector_type(4))) float f32x4;
typedef __attribute__((ext_vector_type(16))) float f32x16;
typedef __attribute__((ext_vector_type(2))) u32 u32x2;
typedef __attribute__((ext_vector_type(4))) u32 u32x4;

#define MFMA16(a, b, c) __builtin_amdgcn_mfma_f32_16x16x32_bf16(a, b, c, 0, 0, 0)
#define MFMA32(a, b, c) __builtin_amdgcn_mfma_f32_32x32x16_bf16(a, b, c, 0, 0, 0)

#if __has_builtin(__builtin_amdgcn_exp2f)
#define EXP2(x) __builtin_amdgcn_exp2f(x)
#else
#define EXP2(x) exp2f(x)
#endif

__device__ inline u16 f2bf(float f) {
    __hip_bfloat16 h = __float2bfloat16(f);
    return *reinterpret_cast<u16*>(&h);
}

// RNE round a,b to bf16 and pack into one u32 (a = low half). No NaN check —
// callers guarantee finite inputs.
__device__ inline u32 rne_pack(float a, float b) {
    u32 ua = __builtin_bit_cast(u32, a), ub = __builtin_bit_cast(u32, b);
    ua = (ua + 0x7fffu + ((ua >> 16) & 1u)) >> 16;
    ub = (ub + 0x7fffu + ((ub >> 16) & 1u)) >> 16;
    return (ub << 16) | ua;
}

// single-instruction packed f32->bf16 RNE convert (no builtin on gfx950; T12)
__device__ inline u32 cvtpk(float a, float b) {
    u32 r;
    asm("v_cvt_pk_bf16_f32 %0, %1, %2" : "=v"(r) : "v"(a), "v"(b));
    return r;
}

// async 16B global->LDS. LDS dest is wave-uniform base; HW adds lane*16.
__device__ inline void gl2lds16(const void* g, void* l) {
    __builtin_amdgcn_global_load_lds((const __attribute__((address_space(1))) void*)g,
                                     (__attribute__((address_space(3))) void*)l, 16, 0, 0);
}

// compiler-fenced raw barrier (NO vmcnt drain — that is the whole point)
__device__ inline void bar() {
    asm volatile("" ::: "memory");
    __builtin_amdgcn_s_barrier();
    asm volatile("" ::: "memory");
}
#define LGKM0 asm volatile("s_waitcnt lgkmcnt(0)" ::: "memory")
#define VM0   asm volatile("s_waitcnt vmcnt(0)" ::: "memory")

// half-swap: x[i] = i<32 ? a[i] : b[i-32]; y[i] = i<32 ? a[i+32] : b[i].
// One v_permlane32_swap_b32 yields both outputs (T12); shfl fallback.
__device__ inline void plswap(u32 a, u32 b, int half, u32& x, u32& y) {
#if __has_builtin(__builtin_amdgcn_permlane32_swap)
    u32x2 r = __builtin_amdgcn_permlane32_swap(a, b, false, false);
    x = r[0]; y = r[1];
#else
    u32 oa = __shfl_xor(a, 32, 64), ob = __shfl_xor(b, 32, 64);
    x = half ? ob : a;
    y = half ? b : oa;
#endif
}

// ---------------------------------------------------------------------------
// One fused cast kernel: x (6144 blocks) + Wq/Wk/Wv -> Wqkv, Wo -> Wob.
// ---------------------------------------------------------------------------
__global__ __launch_bounds__(256) void castall(const float* __restrict__ x,
                                               const float* __restrict__ Wq,
                                               const float* __restrict__ Wk,
                                               const float* __restrict__ Wv,
                                               const float* __restrict__ Wo,
                                               u16* __restrict__ xb,
                                               u16* __restrict__ Wqkv,
                                               u16* __restrict__ Wob) {
    const int WB = (NDIM * NDIM) / 1024; // 576 blocks per weight
    int blk = blockIdx.x;
    const float* s;
    u16* d;
    int base;
    if (blk < 6144) {
        s = x; d = xb; base = blk * 1024;
    } else {
        int wsel = (blk - 6144) / WB, r = (blk - 6144) % WB;
        base = r * 1024;
        if (wsel == 0)      { s = Wq; d = Wqkv; }
        else if (wsel == 1) { s = Wk; d = Wqkv + NDIM * NDIM; }
        else if (wsel == 2) { s = Wv; d = Wqkv + 2 * NDIM * NDIM; }
        else                { s = Wo; d = Wob; }
    }
    int i = base + threadIdx.x * 4;
    float4 v = *(const float4*)(s + i);
    uint2 o = make_uint2(rne_pack(v.x, v.y), rne_pack(v.z, v.w));
    *(uint2*)(d + i) = o;
}

// ---------------------------------------------------------------------------
// 256x256 / BK=64 / 8-wave 8-phase GEMM (T3+T4+T5 template) for the fused
// QKV projection: C = A[8192,768] @ B[2304,768]^T with fused cosine-norm
// (Q/K) and transposed-V epilogue.
//
// Scheduling: 288 output tiles don't fit 256 CUs at 1 blk/CU, so grid = 384:
//   blk 0..255  : full 256^2 tiles over N-tiles 0..7 (exactly one round)
//   blk 256..383: 128x128 quarter-tiles over the last N-strip (V heads 8..11)
// ---------------------------------------------------------------------------
__global__ __launch_bounds__(512, 2) void gemm256_qkv(const u16* __restrict__ A,
                                                      const u16* __restrict__ B,
                                                      u16* __restrict__ Vt,
                                                      const float* __restrict__ s_qk,
                                                      u16* __restrict__ Qdst,
                                                      u16* __restrict__ Kdst) {
    constexpr int K = NDIM;     // 768
    constexpr int NT = K / 64;  // 12 K-tiles
    __shared__ __align__(16) u16 As[2][2][128 * 64]; // [dbuf][half][r*8+slot]
    __shared__ __align__(16) u16 Bs[2][2][128 * 64];

    const int t = threadIdx.x;
    const int wave = t >> 6, lane = t & 63;
    const int quad = lane >> 4, l16 = lane & 15;
    const int fx = l16 & 7;                  // fragment-read XOR key
    const int blk = blockIdx.x;

    // half-tile stage: 128 rows x 64 k = 16 KB = 512 thr x 2 x 16B.
    const int srow = lane >> 3;
    const int schk = (lane & 7) ^ srow;
    auto stg = [&](const u16* src, u16* dst) {
#pragma unroll
        for (int it = 0; it < 2; ++it) {
            const int cb = it * 512 + wave * 64; // slot base, wave-uniform
            const int r = (cb >> 3) + srow;      // row 0..127
            gl2lds16(src + (size_t)r * K + schk * 8, (char*)dst + cb * 16);
        }
    };

    if (blk < 256) {
        // =================== full 256^2 8-phase path ===================
        const int wm = wave >> 2, wn = wave & 3; // 2 x 4 wave grid, 128x64 each
        const int xcd = blk & 7, local = blk >> 3;            // 0..31
        const int bm = xcd * 1024 + (local >> 3) * 256;       // 4 M-tiles/XCD
        const int bn = (local & 7) * 256;                     // N-tiles 0..7

        f32x4 acc[8][4];
#pragma unroll
        for (int i = 0; i < 8; ++i)
#pragma unroll
            for (int j = 0; j < 4; ++j) acc[i][j] = (f32x4){0.f, 0.f, 0.f, 0.f};

        const u16* Ag = A + (size_t)bm * K;
        const u16* Bg = B + (size_t)bn * K;

        // prologue: tile0 {A,B} + tile1 {B}; wait tile0 (12 issued, 4 may fly)
        stg(Ag,                        As[0][0]);
        stg(Ag + (size_t)128 * K,      As[0][1]);
        stg(Bg,                        Bs[0][0]);
        stg(Bg + (size_t)128 * K,      Bs[0][1]);
        stg(Bg + 64,                   Bs[1][0]);
        stg(Bg + (size_t)128 * K + 64, Bs[1][1]);
        asm volatile("s_waitcnt vmcnt(4)" ::: "memory");
        bar();

        short8 a[4][2], b0[2][2], b1[2][2];
        const int rb0 = (wn & 1) * 64; // this wave's B-row base within its half

#pragma unroll 2
        for (int T = 0; T < NT; ++T) {
            const int db = T & 1;
            u16* Asl = As[db][wm];
            u16* Bsl = Bs[db][wn >> 1];
            const u16* An = Ag + (size_t)(T + 1) * 64;
            const u16* Bn = Bg + (size_t)(T + 2) * 64;

            // ---- P0: read A[mi0-3] + B[ni0-1]; stage A(T+1)h0; MFMA Q(0,0) ----
#pragma unroll
            for (int mi = 0; mi < 4; ++mi) {
                const int r = mi * 16 + l16;
#pragma unroll
                for (int kk = 0; kk < 2; ++kk)
                    a[mi][kk] = *(const short8*)&Asl[(r * 8 + ((kk * 4 + quad) ^ fx)) * 8];
            }
#pragma unroll
            for (int ni = 0; ni < 2; ++ni) {
                const int r = rb0 + ni * 16 + l16;
#pragma unroll
                for (int kk = 0; kk < 2; ++kk)
                    b0[ni][kk] = *(const short8*)&Bsl[(r * 8 + ((kk * 4 + quad) ^ fx)) * 8];
            }
            if (T + 1 < NT) stg(An, As[db ^ 1][0]);
            bar();
            LGKM0;
            __builtin_amdgcn_s_setprio(1);
#pragma unroll
            for (int kk = 0; kk < 2; ++kk)
#pragma unroll
                for (int mi = 0; mi < 4; ++mi)
#pragma unroll
                    for (int ni = 0; ni < 2; ++ni)
                        acc[mi][ni] = MFMA16(a[mi][kk], b0[ni][kk], acc[mi][ni]);
            __builtin_amdgcn_s_setprio(0);
            bar();

            // ---- P1: read B[ni2-3]; stage A(T+1)h1; MFMA Q(0,1) ----
#pragma unroll
            for (int ni = 0; ni < 2; ++ni) {
                const int r = rb0 + (ni + 2) * 16 + l16;
#pragma unroll
                for (int kk = 0; kk < 2; ++kk)
                    b1[ni][kk] = *(const short8*)&Bsl[(r * 8 + ((kk * 4 + quad) ^ fx)) * 8];
            }
            if (T + 1 < NT) stg(An + (size_t)128 * K, As[db ^ 1][1]);
            bar();
            LGKM0;
            __builtin_amdgcn_s_setprio(1);
#pragma unroll
            for (int kk = 0; kk < 2; ++kk)
#pragma unroll
                for (int mi = 0; mi < 4; ++mi)
#pragma unroll
                    for (int ni = 0; ni < 2; ++ni)
                        acc[mi][ni + 2] = MFMA16(a[mi][kk], b1[ni][kk], acc[mi][ni + 2]);
            __builtin_amdgcn_s_setprio(0);
            bar();

            // ---- P2: read A[mi4-7]; stage B(T+2)h0; MFMA Q(1,1) ----
#pragma unroll
            for (int mi = 0; mi < 4; ++mi) {
                const int r = (mi + 4) * 16 + l16;
#pragma unroll
                for (int kk = 0; kk < 2; ++kk)
                    a[mi][kk] = *(const short8*)&Asl[(r * 8 + ((kk * 4 + quad) ^ fx)) * 8];
            }
            if (T + 2 < NT) stg(Bn, Bs[db][0]);
            bar();
            LGKM0;
            __builtin_amdgcn_s_setprio(1);
#pragma unroll
            for (int kk = 0; kk < 2; ++kk)
#pragma unroll
                for (int mi = 0; mi < 4; ++mi)
#pragma unroll
                    for (int ni = 0; ni < 2; ++ni)
                        acc[mi + 4][ni + 2] = MFMA16(a[mi][kk], b1[ni][kk], acc[mi + 4][ni + 2]);
            __builtin_amdgcn_s_setprio(0);
            bar();

            // ---- P3: stage B(T+2)h1; MFMA Q(1,0); counted vmcnt; bar ----
            if (T + 2 < NT) stg(Bn + (size_t)128 * K, Bs[db][1]);
            bar();
            __builtin_amdgcn_s_setprio(1);
#pragma unroll
            for (int kk = 0; kk < 2; ++kk)
#pragma unroll
                for (int mi = 0; mi < 4; ++mi)
#pragma unroll
                    for (int ni = 0; ni < 2; ++ni)
                        acc[mi + 4][ni] = MFMA16(a[mi][kk], b0[ni][kk], acc[mi + 4][ni]);
            __builtin_amdgcn_s_setprio(0);
            if (T + 2 < NT) {
                asm volatile("s_waitcnt vmcnt(4)" ::: "memory"); // tile T+1 resident
            } else {
                VM0; // drains A(NT-1) too (last two iters)
            }
            bar();
        }

        // ---- fused QKV epilogue (wave's 64 cols = exactly one head-group) ----
        const int cg = (bn + wn * 64) >> 6; // 0..31 here
        if (cg >= 2 * NHEADS) {
            // V path: transposed bf16 write, 4 consecutive tokens packed -> 8B
            const int h = cg - 2 * NHEADS;
#pragma unroll
            for (int mi = 0; mi < 8; ++mi) {
                const int row = bm + wm * 128 + mi * 16 + quad * 4; // token base
                const int bb = row >> 10, n0 = row & 1023;
#pragma unroll
                for (int ni = 0; ni < 4; ++ni) {
                    const int dd = ni * 16 + l16;
                    uint2 pk = make_uint2(rne_pack(acc[mi][ni][0], acc[mi][ni][1]),
                                          rne_pack(acc[mi][ni][2], acc[mi][ni][3]));
                    *(uint2*)(Vt + (((size_t)(bb * NHEADS + h) * HD + dd) << 10) + n0) = pk;
                }
            }
        } else {
            const bool isq = cg < NHEADS;
            const int h = isq ? cg : cg - NHEADS;
            u16* dst = isq ? Qdst : Kdst;
            const float ex = isq ? 8.f * LOG2E : 1.f;
            float sq[4];
#pragma unroll
            for (int ni = 0; ni < 4; ++ni)
                sq[ni] = s_qk[h * HD + ni * 16 + l16] * SQRT_DIM * ex;
#pragma unroll
            for (int mi = 0; mi < 8; ++mi)
#pragma unroll
                for (int r = 0; r < 4; ++r) {
                    float ss = 0.f;
#pragma unroll
                    for (int ni = 0; ni < 4; ++ni) ss += acc[mi][ni][r] * acc[mi][ni][r];
                    ss += __shfl_xor(ss, 1, 64);
                    ss += __shfl_xor(ss, 2, 64);
                    ss += __shfl_xor(ss, 4, 64);
                    ss += __shfl_xor(ss, 8, 64);
                    float inv = 1.f / fmaxf(sqrtf(ss), 1e-6f);
                    const int row = bm + wm * 128 + mi * 16 + quad * 4 + r;
                    const int bb = row >> 10, tok = row & 1023;
                    u16* o = dst + ((size_t)(bb * NHEADS + h) * SEQ + tok) * HD;
#pragma unroll
                    for (int ni = 0; ni < 4; ++ni)
                        o[ni * 16 + l16] = f2bf(acc[mi][ni][r] * sq[ni] * inv);
                }
        }
    } else {
        // =================== tail: 128x128 quarter-tiles (V heads 8..11) ====
        const int q = blk - 256;                 // 0..127
        const int bm = (q >> 1) * 128;
        const int bn = 2048 + (q & 1) * 128;
        const int wm4 = wave >> 1, wn2 = wave & 1; // 4M x 2N waves, 32x64 each
        const u16* Aq = A + (size_t)bm * K;
        const u16* Bq = B + (size_t)bn * K;

        f32x4 qa[2][4];
#pragma unroll
        for (int i = 0; i < 2; ++i)
#pragma unroll
            for (int j = 0; j < 4; ++j) qa[i][j] = (f32x4){0.f, 0.f, 0.f, 0.f};

        stg(Aq, As[0][0]);
        stg(Bq, Bs[0][0]);
        VM0;
        bar();
#pragma unroll 2
        for (int T = 0; T < NT; ++T) {
            const int db = T & 1;
            if (T + 1 < NT) {
                stg(Aq + (size_t)(T + 1) * 64, As[db ^ 1][0]);
                stg(Bq + (size_t)(T + 1) * 64, Bs[db ^ 1][0]);
            }
            const u16* Asl = As[db][0];
            const u16* Bsl = Bs[db][0];
            short8 af[2][2], bf[4][2];
#pragma unroll
            for (int mi = 0; mi < 2; ++mi) {
                const int r = wm4 * 32 + mi * 16 + l16;
#pragma unroll
                for (int kk = 0; kk < 2; ++kk)
                    af[mi][kk] = *(const short8*)&Asl[(r * 8 + ((kk * 4 + quad) ^ fx)) * 8];
            }
#pragma unroll
            for (int ni = 0; ni < 4; ++ni) {
                const int r = wn2 * 64 + ni * 16 + l16;
#pragma unroll
                for (int kk = 0; kk < 2; ++kk)
                    bf[ni][kk] = *(const short8*)&Bsl[(r * 8 + ((kk * 4 + quad) ^ fx)) * 8];
            }
            __builtin_amdgcn_s_setprio(1);
#pragma unroll
            for (int kk = 0; kk < 2; ++kk)
#pragma unroll
                for (int mi = 0; mi < 2; ++mi)
#pragma unroll
                    for (int ni = 0; ni < 4; ++ni)
                        qa[mi][ni] = MFMA16(af[mi][kk], bf[ni][kk], qa[mi][ni]);
            __builtin_amdgcn_s_setprio(0);
            VM0;
            bar();
        }
        // V epilogue (packed 8B stores), heads 8..11
        const int h = 8 + (q & 1) * 2 + wn2;
#pragma unroll
        for (int mi = 0; mi < 2; ++mi) {
            const int row = bm + wm4 * 32 + mi * 16 + quad * 4;
            const int bb = row >> 10, n0 = row & 1023;
#pragma unroll
            for (int ni = 0; ni < 4; ++ni) {
                const int dd = ni * 16 + l16;
                uint2 pk = make_uint2(rne_pack(qa[mi][ni][0], qa[mi][ni][1]),
                                      rne_pack(qa[mi][ni][2], qa[mi][ni][3]));
                *(uint2*)(Vt + (((size_t)(bb * NHEADS + h) * HD + dd) << 10) + n0) = pk;
            }
        }
    }
}

// ---------------------------------------------------------------------------
// bf16 MFMA GEMM: C = A[M,768] @ B[N,768]^T, fp32 accum. 128x128 tile,
// double-buffered BK=32 (one barrier/iter). Kept for the output projection.
// ---------------------------------------------------------------------------
template <int EPI>
__global__ __launch_bounds__(256) void gemm_bf16(const u16* __restrict__ A,
                                                 const u16* __restrict__ B,
                                                 void* __restrict__ C, int N,
                                                 const float* __restrict__ s_qk,
                                                 u16* __restrict__ Qdst,
                                                 u16* __restrict__ Kdst,
                                                 int NX) {
    constexpr int K = NDIM;
    constexpr int NKT = K / 32; // 24 K-tiles
    __shared__ __align__(16) u16 As[2][4096]; // 8 KB per buffer
    __shared__ __align__(16) u16 Bs[2][4096];
    const int t = threadIdx.x;
    const int wave = t >> 6, lane = t & 63;
    const int quad = lane >> 4, l16 = lane & 15;
    const int wx = (wave & 1) * 64, wy = (wave >> 1) * 64;
    const int blk = blockIdx.x;
    const int xcd = blk & 7, local = blk >> 3;
    const int bm = (xcd * 8 + local / NX) * 128;
    const int bn = (local % NX) * 128;

    f32x4 acc[4][4];
#pragma unroll
    for (int i = 0; i < 4; ++i)
#pragma unroll
        for (int j = 0; j < 4; ++j) acc[i][j] = (f32x4){0.f, 0.f, 0.f, 0.f};

    const int srl = lane >> 2;
    const int skc = (lane & 3) ^ ((lane >> 3) & 3);
    auto stage = [&](int k0, int bsel) {
#pragma unroll
        for (int it = 0; it < 2; ++it) {
            const int cb = it * 256 + wave * 64;
            const int row = (cb >> 6) * 16 + srl;
            gl2lds16(A + (size_t)(bm + row) * K + k0 + skc * 8,
                     (char*)As[bsel] + cb * 16);
            gl2lds16(B + (size_t)(bn + row) * K + k0 + skc * 8,
                     (char*)Bs[bsel] + cb * 16);
        }
    };
    const int fxor = (l16 >> 1) & 3;

    stage(0, 0);
#pragma unroll
    for (int kt = 0; kt < NKT; ++kt) {
        __syncthreads();
        if (kt + 1 < NKT) stage((kt + 1) * 32, (kt + 1) & 1);
        const int b = kt & 1;
        short8 af[4], bfr[4];
#pragma unroll
        for (int i = 0; i < 4; ++i)
            af[i] = *(const short8*)&As[b][
                ((((wy >> 4) + i) * 64 + l16 * 4 + (quad ^ fxor)) * 8)];
#pragma unroll
        for (int j = 0; j < 4; ++j)
            bfr[j] = *(const short8*)&Bs[b][
                ((((wx >> 4) + j) * 64 + l16 * 4 + (quad ^ fxor)) * 8)];
#pragma unroll
        for (int i = 0; i < 4; ++i)
#pragma unroll
            for (int j = 0; j < 4; ++j) acc[i][j] = MFMA16(af[i], bfr[j], acc[i][j]);
    }

    if constexpr (EPI == 0) {
#pragma unroll
        for (int i = 0; i < 4; ++i)
#pragma unroll
            for (int j = 0; j < 4; ++j)
#pragma unroll
                for (int r = 0; r < 4; ++r) {
                    const int row = bm + wy + i * 16 + quad * 4 + r;
                    const int col = bn + wx + j * 16 + l16;
                    ((float*)C)[(size_t)row * N + col] = acc[i][j][r];
                }
    }
}

// ---------------------------------------------------------------------------
// MFMA flash attention, 32x32x16, no-max softmax. 256 threads = 4 waves;
// each wave owns 32 queries -> block = 128 queries; streams 64-key tiles.
//
// r4: __launch_bounds__(256,3) — r3 shipped at VGPR_Count=64 (compiler cap)
// with ~100 live values -> remat/mov VALU storm (VALUBusy 48%, MfmaUtil 19%,
// time flat). 3 waves/EU keeps the grid's 3 blocks/CU while allowing ~168
// VGPR. Plus: v_cvt_pk_bf16_f32 packing (1 instr vs 12-op rne_pack), both
// S^T chains issued before softmax (ILP), jt-loop unrolled x2.
// ---------------------------------------------------------------------------
__global__ __launch_bounds__(256, 3) void attn_mfma(const u16* __restrict__ Qh,
                                                    const u16* __restrict__ Kh,
                                                    const u16* __restrict__ Vt,
                                                    u16* __restrict__ AO) {
    __shared__ __align__(16) u16 Ks[2][512 * 8];
    __shared__ __align__(16) u16 Vs[2][512 * 8];

    const int t = threadIdx.x;
    const int wave = t >> 6, lane = t & 63;
    const int l31 = lane & 31, half = lane >> 5;

    // XCD-grouped decode: bid&7 -> XCD slot; 12 (b,h) per XCD; 8 q-blocks each
    const int bid = blockIdx.x;
    const int xcd = bid & 7, idx = bid >> 3;      // idx 0..95
    const int bh = xcd * 12 + (idx % 12);
    const int q0 = (idx / 12) * 128;
    const int b = bh / NHEADS, h = bh - b * NHEADS;

    const u16* Kb = Kh + (size_t)bh * SEQ * HD;
    const u16* Vb = Vt + (size_t)bh * HD * SEQ;
    const int qb = q0 + wave * 32;

    // Q fragments (B-operand: n = query = l31, k = tt*16 + half*8 + j)
    short8 qf[4];
#pragma unroll
    for (int tt = 0; tt < 4; ++tt)
        qf[tt] = *(const short8*)(Qh + ((size_t)bh * SEQ + qb + l31) * HD +
                                  tt * 16 + half * 8);

    f32x16 o[2]; // [d-tile]
#pragma unroll
    for (int dt = 0; dt < 2; ++dt)
#pragma unroll
        for (int r = 0; r < 16; ++r) o[dt][r] = 0.f;
    float lp = 0.f;

    // staging lane->global mapping (inverse of slot swizzle)
    const int arl = lane >> 3;            // row within 8-row span
    const int acc8 = (lane & 7) ^ arl;    // chunk 0..7
    // fragment-read bank spread piece
    const int fx8 = l31 & 7;

    auto stage = [&](int j0, int db) {
#pragma unroll
        for (int it = 0; it < 2; ++it) {
            const int cb = it * 256 + wave * 64; // span base, wave-uniform
            const int r0 = (cb >> 6) * 8 + arl;  // row 0..63
            gl2lds16(Kb + (size_t)(j0 + r0) * HD + acc8 * 8,
                     (char*)Ks[db] + cb * 16);
            gl2lds16(Vb + (size_t)r0 * SEQ + j0 + acc8 * 8,
                     (char*)Vs[db] + cb * 16);
        }
    };

    stage(0, 0);
#pragma unroll 2
    for (int jt = 0; jt < SEQ / 64; ++jt) {
        const int db = jt & 1;
        VM0;   // own tile-jt loads done (issued one full compute phase ago)
        bar(); // all waves' loads landed; all waves done reading buf db^1
        if (jt + 1 < SEQ / 64) stage((jt + 1) * 64, db ^ 1);
        const u16* Ksl = Ks[db];
        const u16* Vsl = Vs[db];

        // ---- S^T: both 32-key tiles, independent MFMA chains first ----
        f32x16 sa0, sa1;
#pragma unroll
        for (int r = 0; r < 16; ++r) { sa0[r] = 0.f; sa1[r] = 0.f; }
#pragma unroll
        for (int tt = 0; tt < 4; ++tt) {
            short8 kf0 = *(const short8*)&Ksl[
                ((((l31 >> 3)) * 64) + fx8 * 8 + ((2 * tt + half) ^ fx8)) * 8];
            short8 kf1 = *(const short8*)&Ksl[
                (((4 + (l31 >> 3)) * 64) + fx8 * 8 + ((2 * tt + half) ^ fx8)) * 8];
            sa0 = MFMA32(kf0, qf[tt], sa0);
            sa1 = MFMA32(kf1, qf[tt], sa1);
        }

        // ---- softmax numerators in-register (exp2 -> cvt_pk -> permlane) ----
        short8 pf0a, pf0b, pf1a, pf1b;
        {
            float p[16];
#pragma unroll
            for (int r = 0; r < 16; ++r) p[r] = EXP2(sa0[r]);
#pragma unroll
            for (int rg = 0; rg < 4; ++rg)
                lp += (p[rg * 4] + p[rg * 4 + 1]) + (p[rg * 4 + 2] + p[rg * 4 + 3]);
            u32 q[8];
#pragma unroll
            for (int i = 0; i < 8; ++i) q[i] = cvtpk(p[2 * i], p[2 * i + 1]);
            u32 d0, d1, d2, d3, e0, e1, e2, e3;
            plswap(q[0], q[2], half, d0, d2);
            plswap(q[1], q[3], half, d1, d3);
            plswap(q[4], q[6], half, e0, e2);
            plswap(q[5], q[7], half, e1, e3);
            u32x4 f0v = {d0, d1, d2, d3};
            u32x4 f1v = {e0, e1, e2, e3};
            pf0a = __builtin_bit_cast(short8, f0v);
            pf0b = __builtin_bit_cast(short8, f1v);
        }
        {
            float p[16];
#pragma unroll
            for (int r = 0; r < 16; ++r) p[r] = EXP2(sa1[r]);
#pragma unroll
            for (int rg = 0; rg < 4; ++rg)
                lp += (p[rg * 4] + p[rg * 4 + 1]) + (p[rg * 4 + 2] + p[rg * 4 + 3]);
            u32 q[8];
#pragma unroll
            for (int i = 0; i < 8; ++i) q[i] = cvtpk(p[2 * i], p[2 * i + 1]);
            u32 d0, d1, d2, d3, e0, e1, e2, e3;
            plswap(q[0], q[2], half, d0, d2);
            plswap(q[1], q[3], half, d1, d3);
            plswap(q[4], q[6], half, e0, e2);
            plswap(q[5], q[7], half, e1, e3);
            u32x4 f0v = {d0, d1, d2, d3};
            u32x4 f1v = {e0, e1, e2, e3};
            pf1a = __builtin_bit_cast(short8, f0v);
            pf1b = __builtin_bit_cast(short8, f1v);
        }

        // ---- PV: O^T += V^T @ P (4 slices of 16 keys) ----
#pragma unroll
        for (int kt = 0; kt < 2; ++kt)
#pragma unroll
            for (int s = 0; s < 2; ++s) {
                short8 pf = kt ? (s ? pf1b : pf1a) : (s ? pf0b : pf0a);
                const int c = kt * 4 + s * 2 + half; // key-slice column
#pragma unroll
                for (int dt = 0; dt < 2; ++dt) {
                    short8 vf = *(const short8*)&Vsl[
                        (((dt * 4 + (l31 >> 3)) * 64) + fx8 * 8 + (c ^ fx8)) * 8];
                    o[dt] = MFMA32(vf, pf, o[dt]);
                }
            }
    }

    // final l reduction (halves hold disjoint key subsets) and output
    const float invl = 1.f / (lp + __shfl_xor(lp, 32, 64));
    u16* ob = AO + (size_t)(b * SEQ + qb + l31) * NDIM + h * HD;
#pragma unroll
    for (int dt = 0; dt < 2; ++dt)
#pragma unroll
        for (int rg = 0; rg < 4; ++rg) {
            bf16x4 ok = {(short)f2bf(o[dt][rg * 4 + 0] * invl),
                         (short)f2bf(o[dt][rg * 4 + 1] * invl),
                         (short)f2bf(o[dt][rg * 4 + 2] * invl),
                         (short)f2bf(o[dt][rg * 4 + 3] * invl)};
            *(bf16x4*)(ob + dt * 32 + rg * 8 + half * 4) = ok;
        }
}

// ---------------------------------------------------------------------------
extern "C" void kernel_launch(void* const* d_in, const int* in_sizes, int n_in,
                              void* d_out, int out_size, void* d_ws, size_t ws_size,
                              hipStream_t stream) {
    const float* x    = (const float*)d_in[0];
    const float* Wq   = (const float*)d_in[1];
    const float* Wk   = (const float*)d_in[2];
    const float* Wv   = (const float*)d_in[3];
    const float* Wo   = (const float*)d_in[4];
    const float* s_qk = (const float*)d_in[5];
    float* out = (float*)d_out;

    char* w = (char*)d_ws;
    const size_t TE = (size_t)MROWS * NDIM;
    u16* xb   = (u16*)w;                    w += TE * 2;
    u16* Wqkv = (u16*)w;                    w += (size_t)3 * NDIM * NDIM * 2;
    u16* Wob  = (u16*)w;                    w += (size_t)NDIM * NDIM * 2;
    u16* Qh   = (u16*)w;                    w += TE * 2;
    u16* Kh   = (u16*)w;                    w += TE * 2;
    u16* Vt   = (u16*)w;                    w += TE * 2;
    u16* ao   = (u16*)w;

    castall<<<6144 + 4 * 576, 256, 0, stream>>>(x, Wq, Wk, Wv, Wo, xb, Wqkv, Wob);

    // Fused QKV projection: 256 full 256^2 tiles (one round) + 128 quarter
    // tiles that fill the scheduling tail.
    gemm256_qkv<<<384, 512, 0, stream>>>(xb, Wqkv, Vt, s_qk, Qh, Kh);

    // Flash attention, XCD-grouped 1D grid (768 = 8 xcd x 12 bh x 8 qblk)
    attn_mfma<<<768, 256, 0, stream>>>(Qh, Kh, Vt, ao);

    // Output projection: NX = 768/128 = 6
    gemm_bf16<0><<<6 * 64, 256, 0, stream>>>(
        ao, Wob, out, NDIM, nullptr, nullptr, nullptr, 6);
}

// Round 5
// 177.114 us; speedup vs baseline: 1.1478x; 1.0119x over previous
//
#include <hip/hip_runtime.h>
#include <hip/hip_bf16.h>
#include <math.h>

#define NDIM 768
#define NHEADS 12
#define HD 64
#define SEQ 1024
#define BATCH 8
#define MROWS (BATCH * SEQ)          // 8192
#define SQRT_DIM 27.712812921102035f // 1/SCALE_PARAM_INIT
#define LOG2E 1.4426950408889634f

typedef unsigned short u16;
typedef unsigned int u32;
typedef __attribute__((ext_vector_type(8))) short short8;   // 8 bf16 = 4 VGPRs
typedef __attribute__((ext_vector_type(4))) short bf16x4;   // 4 bf16 = 2 VGPRs
typedef __attribute__((ext_vector_type(4))) float f32x4;
typedef __attribute__((ext_vector_type(16))) float f32x16;
typedef __attribute__((ext_vector_type(2))) u32 u32x2;
typedef __attribute__((ext_vector_type(4))) u32 u32x4;

#define MFMA16(a, b, c) __builtin_amdgcn_mfma_f32_16x16x32_bf16(a, b, c, 0, 0, 0)
#define MFMA32(a, b, c) __builtin_amdgcn_mfma_f32_32x32x16_bf16(a, b, c, 0, 0, 0)

#if __has_builtin(__builtin_amdgcn_exp2f)
#define EXP2(x) __builtin_amdgcn_exp2f(x)
#else
#define EXP2(x) exp2f(x)
#endif

__device__ inline u16 f2bf(float f) {
    __hip_bfloat16 h = __float2bfloat16(f);
    return *reinterpret_cast<u16*>(&h);
}

// RNE round a,b to bf16 and pack into one u32 (a = low half). No NaN check —
// callers guarantee finite inputs.
__device__ inline u32 rne_pack(float a, float b) {
    u32 ua = __builtin_bit_cast(u32, a), ub = __builtin_bit_cast(u32, b);
    ua = (ua + 0x7fffu + ((ua >> 16) & 1u)) >> 16;
    ub = (ub + 0x7fffu + ((ub >> 16) & 1u)) >> 16;
    return (ub << 16) | ua;
}

// single-instruction packed f32->bf16 RNE convert (no builtin on gfx950; T12)
__device__ inline u32 cvtpk(float a, float b) {
    u32 r;
    asm("v_cvt_pk_bf16_f32 %0, %1, %2" : "=v"(r) : "v"(a), "v"(b));
    return r;
}

// async 16B global->LDS. LDS dest is wave-uniform base; HW adds lane*16.
__device__ inline void gl2lds16(const void* g, void* l) {
    __builtin_amdgcn_global_load_lds((const __attribute__((address_space(1))) void*)g,
                                     (__attribute__((address_space(3))) void*)l, 16, 0, 0);
}

// compiler-fenced raw barrier (NO vmcnt drain — that is the whole point)
__device__ inline void bar() {
    asm volatile("" ::: "memory");
    __builtin_amdgcn_s_barrier();
    asm volatile("" ::: "memory");
}
#define LGKM0 asm volatile("s_waitcnt lgkmcnt(0)" ::: "memory")
#define VM0   asm volatile("s_waitcnt vmcnt(0)" ::: "memory")

// half-swap: x[i] = i<32 ? a[i] : b[i-32]; y[i] = i<32 ? a[i+32] : b[i].
// One v_permlane32_swap_b32 yields both outputs (T12); shfl fallback.
__device__ inline void plswap(u32 a, u32 b, int half, u32& x, u32& y) {
#if __has_builtin(__builtin_amdgcn_permlane32_swap)
    u32x2 r = __builtin_amdgcn_permlane32_swap(a, b, false, false);
    x = r[0]; y = r[1];
#else
    u32 oa = __shfl_xor(a, 32, 64), ob = __shfl_xor(b, 32, 64);
    x = half ? ob : a;
    y = half ? b : oa;
#endif
}

// ---------------------------------------------------------------------------
// One fused cast kernel: x (6144 blocks) + Wq/Wk/Wv -> Wqkv, Wo -> Wob.
// ---------------------------------------------------------------------------
__global__ __launch_bounds__(256) void castall(const float* __restrict__ x,
                                               const float* __restrict__ Wq,
                                               const float* __restrict__ Wk,
                                               const float* __restrict__ Wv,
                                               const float* __restrict__ Wo,
                                               u16* __restrict__ xb,
                                               u16* __restrict__ Wqkv,
                                               u16* __restrict__ Wob) {
    const int WB = (NDIM * NDIM) / 1024; // 576 blocks per weight
    int blk = blockIdx.x;
    const float* s;
    u16* d;
    int base;
    if (blk < 6144) {
        s = x; d = xb; base = blk * 1024;
    } else {
        int wsel = (blk - 6144) / WB, r = (blk - 6144) % WB;
        base = r * 1024;
        if (wsel == 0)      { s = Wq; d = Wqkv; }
        else if (wsel == 1) { s = Wk; d = Wqkv + NDIM * NDIM; }
        else if (wsel == 2) { s = Wv; d = Wqkv + 2 * NDIM * NDIM; }
        else                { s = Wo; d = Wob; }
    }
    int i = base + threadIdx.x * 4;
    float4 v = *(const float4*)(s + i);
    uint2 o = make_uint2(rne_pack(v.x, v.y), rne_pack(v.z, v.w));
    *(uint2*)(d + i) = o;
}

// ---------------------------------------------------------------------------
// 256x256 / BK=64 / 8-wave 8-phase GEMM (T3+T4+T5 template) for the fused
// QKV projection: C = A[8192,768] @ B[2304,768]^T with fused cosine-norm
// (Q/K) and transposed-V epilogue.
//
// Scheduling: grid = 384:
//   blk 0..255  : full 256^2 tiles over N-tiles 0..7 (exactly one round)
//   blk 256..383: 128x128 quarter-tiles over the last N-strip (V heads 8..11)
//                 r5: 4-deep LDS ring + counted vmcnt(8) (the r4 per-iter
//                 vmcnt(0) drain exposed full HBM latency x12 -> ~19 us tail).
// ---------------------------------------------------------------------------
__global__ __launch_bounds__(512, 2) void gemm256_qkv(const u16* __restrict__ A,
                                                      const u16* __restrict__ B,
                                                      u16* __restrict__ Vt,
                                                      const float* __restrict__ s_qk,
                                                      u16* __restrict__ Qdst,
                                                      u16* __restrict__ Kdst) {
    constexpr int K = NDIM;     // 768
    constexpr int NT = K / 64;  // 12 K-tiles
    __shared__ __align__(16) u16 As[2][2][128 * 64]; // [dbuf][half][r*8+slot]
    __shared__ __align__(16) u16 Bs[2][2][128 * 64];

    const int t = threadIdx.x;
    const int wave = t >> 6, lane = t & 63;
    const int quad = lane >> 4, l16 = lane & 15;
    const int fx = l16 & 7;                  // fragment-read XOR key
    const int blk = blockIdx.x;

    // half-tile stage: 128 rows x 64 k = 16 KB = 512 thr x 2 x 16B.
    const int srow = lane >> 3;
    const int schk = (lane & 7) ^ srow;
    auto stg = [&](const u16* src, u16* dst) {
#pragma unroll
        for (int it = 0; it < 2; ++it) {
            const int cb = it * 512 + wave * 64; // slot base, wave-uniform
            const int r = (cb >> 3) + srow;      // row 0..127
            gl2lds16(src + (size_t)r * K + schk * 8, (char*)dst + cb * 16);
        }
    };

    if (blk < 256) {
        // =================== full 256^2 8-phase path ===================
        const int wm = wave >> 2, wn = wave & 3; // 2 x 4 wave grid, 128x64 each
        const int xcd = blk & 7, local = blk >> 3;            // 0..31
        const int bm = xcd * 1024 + (local >> 3) * 256;       // 4 M-tiles/XCD
        const int bn = (local & 7) * 256;                     // N-tiles 0..7

        f32x4 acc[8][4];
#pragma unroll
        for (int i = 0; i < 8; ++i)
#pragma unroll
            for (int j = 0; j < 4; ++j) acc[i][j] = (f32x4){0.f, 0.f, 0.f, 0.f};

        const u16* Ag = A + (size_t)bm * K;
        const u16* Bg = B + (size_t)bn * K;

        // prologue: tile0 {A,B} + tile1 {B}; wait tile0 (12 issued, 4 may fly)
        stg(Ag,                        As[0][0]);
        stg(Ag + (size_t)128 * K,      As[0][1]);
        stg(Bg,                        Bs[0][0]);
        stg(Bg + (size_t)128 * K,      Bs[0][1]);
        stg(Bg + 64,                   Bs[1][0]);
        stg(Bg + (size_t)128 * K + 64, Bs[1][1]);
        asm volatile("s_waitcnt vmcnt(4)" ::: "memory");
        bar();

        short8 a[4][2], b0[2][2], b1[2][2];
        const int rb0 = (wn & 1) * 64; // this wave's B-row base within its half

#pragma unroll 2
        for (int T = 0; T < NT; ++T) {
            const int db = T & 1;
            u16* Asl = As[db][wm];
            u16* Bsl = Bs[db][wn >> 1];
            const u16* An = Ag + (size_t)(T + 1) * 64;
            const u16* Bn = Bg + (size_t)(T + 2) * 64;

            // ---- P0: read A[mi0-3] + B[ni0-1]; stage A(T+1)h0; MFMA Q(0,0) ----
#pragma unroll
            for (int mi = 0; mi < 4; ++mi) {
                const int r = mi * 16 + l16;
#pragma unroll
                for (int kk = 0; kk < 2; ++kk)
                    a[mi][kk] = *(const short8*)&Asl[(r * 8 + ((kk * 4 + quad) ^ fx)) * 8];
            }
#pragma unroll
            for (int ni = 0; ni < 2; ++ni) {
                const int r = rb0 + ni * 16 + l16;
#pragma unroll
                for (int kk = 0; kk < 2; ++kk)
                    b0[ni][kk] = *(const short8*)&Bsl[(r * 8 + ((kk * 4 + quad) ^ fx)) * 8];
            }
            if (T + 1 < NT) stg(An, As[db ^ 1][0]);
            bar();
            LGKM0;
            __builtin_amdgcn_s_setprio(1);
#pragma unroll
            for (int kk = 0; kk < 2; ++kk)
#pragma unroll
                for (int mi = 0; mi < 4; ++mi)
#pragma unroll
                    for (int ni = 0; ni < 2; ++ni)
                        acc[mi][ni] = MFMA16(a[mi][kk], b0[ni][kk], acc[mi][ni]);
            __builtin_amdgcn_s_setprio(0);
            bar();

            // ---- P1: read B[ni2-3]; stage A(T+1)h1; MFMA Q(0,1) ----
#pragma unroll
            for (int ni = 0; ni < 2; ++ni) {
                const int r = rb0 + (ni + 2) * 16 + l16;
#pragma unroll
                for (int kk = 0; kk < 2; ++kk)
                    b1[ni][kk] = *(const short8*)&Bsl[(r * 8 + ((kk * 4 + quad) ^ fx)) * 8];
            }
            if (T + 1 < NT) stg(An + (size_t)128 * K, As[db ^ 1][1]);
            bar();
            LGKM0;
            __builtin_amdgcn_s_setprio(1);
#pragma unroll
            for (int kk = 0; kk < 2; ++kk)
#pragma unroll
                for (int mi = 0; mi < 4; ++mi)
#pragma unroll
                    for (int ni = 0; ni < 2; ++ni)
                        acc[mi][ni + 2] = MFMA16(a[mi][kk], b1[ni][kk], acc[mi][ni + 2]);
            __builtin_amdgcn_s_setprio(0);
            bar();

            // ---- P2: read A[mi4-7]; stage B(T+2)h0; MFMA Q(1,1) ----
#pragma unroll
            for (int mi = 0; mi < 4; ++mi) {
                const int r = (mi + 4) * 16 + l16;
#pragma unroll
                for (int kk = 0; kk < 2; ++kk)
                    a[mi][kk] = *(const short8*)&Asl[(r * 8 + ((kk * 4 + quad) ^ fx)) * 8];
            }
            if (T + 2 < NT) stg(Bn, Bs[db][0]);
            bar();
            LGKM0;
            __builtin_amdgcn_s_setprio(1);
#pragma unroll
            for (int kk = 0; kk < 2; ++kk)
#pragma unroll
                for (int mi = 0; mi < 4; ++mi)
#pragma unroll
                    for (int ni = 0; ni < 2; ++ni)
                        acc[mi + 4][ni + 2] = MFMA16(a[mi][kk], b1[ni][kk], acc[mi + 4][ni + 2]);
            __builtin_amdgcn_s_setprio(0);
            bar();

            // ---- P3: stage B(T+2)h1; MFMA Q(1,0); counted vmcnt; bar ----
            if (T + 2 < NT) stg(Bn + (size_t)128 * K, Bs[db][1]);
            bar();
            __builtin_amdgcn_s_setprio(1);
#pragma unroll
            for (int kk = 0; kk < 2; ++kk)
#pragma unroll
                for (int mi = 0; mi < 4; ++mi)
#pragma unroll
                    for (int ni = 0; ni < 2; ++ni)
                        acc[mi + 4][ni] = MFMA16(a[mi][kk], b0[ni][kk], acc[mi + 4][ni]);
            __builtin_amdgcn_s_setprio(0);
            if (T + 2 < NT) {
                asm volatile("s_waitcnt vmcnt(4)" ::: "memory"); // tile T+1 resident
            } else {
                VM0; // drains A(NT-1) too (last two iters)
            }
            bar();
        }

        // ---- fused QKV epilogue (wave's 64 cols = exactly one head-group) ----
        const int cg = (bn + wn * 64) >> 6; // 0..31 here
        if (cg >= 2 * NHEADS) {
            // V path: transposed bf16 write, 4 consecutive tokens packed -> 8B
            const int h = cg - 2 * NHEADS;
#pragma unroll
            for (int mi = 0; mi < 8; ++mi) {
                const int row = bm + wm * 128 + mi * 16 + quad * 4; // token base
                const int bb = row >> 10, n0 = row & 1023;
#pragma unroll
                for (int ni = 0; ni < 4; ++ni) {
                    const int dd = ni * 16 + l16;
                    uint2 pk = make_uint2(rne_pack(acc[mi][ni][0], acc[mi][ni][1]),
                                          rne_pack(acc[mi][ni][2], acc[mi][ni][3]));
                    *(uint2*)(Vt + (((size_t)(bb * NHEADS + h) * HD + dd) << 10) + n0) = pk;
                }
            }
        } else {
            const bool isq = cg < NHEADS;
            const int h = isq ? cg : cg - NHEADS;
            u16* dst = isq ? Qdst : Kdst;
            const float ex = isq ? 8.f * LOG2E : 1.f;
            float sq[4];
#pragma unroll
            for (int ni = 0; ni < 4; ++ni)
                sq[ni] = s_qk[h * HD + ni * 16 + l16] * SQRT_DIM * ex;
#pragma unroll
            for (int mi = 0; mi < 8; ++mi)
#pragma unroll
                for (int r = 0; r < 4; ++r) {
                    float ss = 0.f;
#pragma unroll
                    for (int ni = 0; ni < 4; ++ni) ss += acc[mi][ni][r] * acc[mi][ni][r];
                    ss += __shfl_xor(ss, 1, 64);
                    ss += __shfl_xor(ss, 2, 64);
                    ss += __shfl_xor(ss, 4, 64);
                    ss += __shfl_xor(ss, 8, 64);
                    float inv = 1.f / fmaxf(sqrtf(ss), 1e-6f);
                    const int row = bm + wm * 128 + mi * 16 + quad * 4 + r;
                    const int bb = row >> 10, tok = row & 1023;
                    u16* o = dst + ((size_t)(bb * NHEADS + h) * SEQ + tok) * HD;
#pragma unroll
                    for (int ni = 0; ni < 4; ++ni)
                        o[ni * 16 + l16] = f2bf(acc[mi][ni][r] * sq[ni] * inv);
                }
        }
    } else {
        // ======= tail: 128x128 quarter-tiles, 4-deep ring + counted vmcnt ===
        const int q = blk - 256;                 // 0..127
        const int bm = (q >> 1) * 128;
        const int bn = 2048 + (q & 1) * 128;
        const int wm4 = wave >> 1, wn2 = wave & 1; // 4M x 2N waves, 32x64 each
        const u16* Aq = A + (size_t)bm * K;
        const u16* Bq = B + (size_t)bn * K;
        u16* Abase = &As[0][0][0]; // 4 ring slots of 8192 u16 (16 KB) each
        u16* Bbase = &Bs[0][0][0];

        f32x4 qa[2][4];
#pragma unroll
        for (int i = 0; i < 2; ++i)
#pragma unroll
            for (int j = 0; j < 4; ++j) qa[i][j] = (f32x4){0.f, 0.f, 0.f, 0.f};

        // prologue: stage tiles 0,1,2 (12 VMEM/thread in flight)
        stg(Aq,       Abase);
        stg(Bq,       Bbase);
        stg(Aq + 64,  Abase + 8192);
        stg(Bq + 64,  Bbase + 8192);
        stg(Aq + 128, Abase + 2 * 8192);
        stg(Bq + 128, Bbase + 2 * 8192);

#pragma unroll
        for (int T = 0; T < NT; ++T) {
            // tile T resident: 4 loads per staged tile; tiles T..min(T+2,NT-1)
            // outstanding at this point -> wait 4*(staged_max - T).
            if (T + 2 < NT)      asm volatile("s_waitcnt vmcnt(8)" ::: "memory");
            else if (T + 1 < NT) asm volatile("s_waitcnt vmcnt(4)" ::: "memory");
            else                 VM0;
            bar(); // every wave drained its own tile-T loads -> tile T complete;
                   // also: all waves finished reading slot (T-1)&3 == (T+3)&3
            if (T + 3 < NT) {
                stg(Aq + (size_t)(T + 3) * 64, Abase + ((T + 3) & 3) * 8192);
                stg(Bq + (size_t)(T + 3) * 64, Bbase + ((T + 3) & 3) * 8192);
            }
            const u16* Asl = Abase + (T & 3) * 8192;
            const u16* Bsl = Bbase + (T & 3) * 8192;
            short8 af[2][2], bf[4][2];
#pragma unroll
            for (int mi = 0; mi < 2; ++mi) {
                const int r = wm4 * 32 + mi * 16 + l16;
#pragma unroll
                for (int kk = 0; kk < 2; ++kk)
                    af[mi][kk] = *(const short8*)&Asl[(r * 8 + ((kk * 4 + quad) ^ fx)) * 8];
            }
#pragma unroll
            for (int ni = 0; ni < 4; ++ni) {
                const int r = wn2 * 64 + ni * 16 + l16;
#pragma unroll
                for (int kk = 0; kk < 2; ++kk)
                    bf[ni][kk] = *(const short8*)&Bsl[(r * 8 + ((kk * 4 + quad) ^ fx)) * 8];
            }
            __builtin_amdgcn_s_setprio(1);
#pragma unroll
            for (int kk = 0; kk < 2; ++kk)
#pragma unroll
                for (int mi = 0; mi < 2; ++mi)
#pragma unroll
                    for (int ni = 0; ni < 4; ++ni)
                        qa[mi][ni] = MFMA16(af[mi][kk], bf[ni][kk], qa[mi][ni]);
            __builtin_amdgcn_s_setprio(0);
        }
        // V epilogue (packed 8B stores), heads 8..11
        const int h = 8 + (q & 1) * 2 + wn2;
#pragma unroll
        for (int mi = 0; mi < 2; ++mi) {
            const int row = bm + wm4 * 32 + mi * 16 + quad * 4;
            const int bb = row >> 10, n0 = row & 1023;
#pragma unroll
            for (int ni = 0; ni < 4; ++ni) {
                const int dd = ni * 16 + l16;
                uint2 pk = make_uint2(rne_pack(qa[mi][ni][0], qa[mi][ni][1]),
                                      rne_pack(qa[mi][ni][2], qa[mi][ni][3]));
                *(uint2*)(Vt + (((size_t)(bb * NHEADS + h) * HD + dd) << 10) + n0) = pk;
            }
        }
    }
}

// ---------------------------------------------------------------------------
// bf16 MFMA GEMM: C = A[M,768] @ B[N,768]^T, fp32 accum. 128x128 tile,
// double-buffered BK=32 (one barrier/iter). Kept for the output projection.
// ---------------------------------------------------------------------------
template <int EPI>
__global__ __launch_bounds__(256) void gemm_bf16(const u16* __restrict__ A,
                                                 const u16* __restrict__ B,
                                                 void* __restrict__ C, int N,
                                                 const float* __restrict__ s_qk,
                                                 u16* __restrict__ Qdst,
                                                 u16* __restrict__ Kdst,
                                                 int NX) {
    constexpr int K = NDIM;
    constexpr int NKT = K / 32; // 24 K-tiles
    __shared__ __align__(16) u16 As[2][4096]; // 8 KB per buffer
    __shared__ __align__(16) u16 Bs[2][4096];
    const int t = threadIdx.x;
    const int wave = t >> 6, lane = t & 63;
    const int quad = lane >> 4, l16 = lane & 15;
    const int wx = (wave & 1) * 64, wy = (wave >> 1) * 64;
    const int blk = blockIdx.x;
    const int xcd = blk & 7, local = blk >> 3;
    const int bm = (xcd * 8 + local / NX) * 128;
    const int bn = (local % NX) * 128;

    f32x4 acc[4][4];
#pragma unroll
    for (int i = 0; i < 4; ++i)
#pragma unroll
        for (int j = 0; j < 4; ++j) acc[i][j] = (f32x4){0.f, 0.f, 0.f, 0.f};

    const int srl = lane >> 2;
    const int skc = (lane & 3) ^ ((lane >> 3) & 3);
    auto stage = [&](int k0, int bsel) {
#pragma unroll
        for (int it = 0; it < 2; ++it) {
            const int cb = it * 256 + wave * 64;
            const int row = (cb >> 6) * 16 + srl;
            gl2lds16(A + (size_t)(bm + row) * K + k0 + skc * 8,
                     (char*)As[bsel] + cb * 16);
            gl2lds16(B + (size_t)(bn + row) * K + k0 + skc * 8,
                     (char*)Bs[bsel] + cb * 16);
        }
    };
    const int fxor = (l16 >> 1) & 3;

    stage(0, 0);
#pragma unroll
    for (int kt = 0; kt < NKT; ++kt) {
        __syncthreads();
        if (kt + 1 < NKT) stage((kt + 1) * 32, (kt + 1) & 1);
        const int b = kt & 1;
        short8 af[4], bfr[4];
#pragma unroll
        for (int i = 0; i < 4; ++i)
            af[i] = *(const short8*)&As[b][
                ((((wy >> 4) + i) * 64 + l16 * 4 + (quad ^ fxor)) * 8)];
#pragma unroll
        for (int j = 0; j < 4; ++j)
            bfr[j] = *(const short8*)&Bs[b][
                ((((wx >> 4) + j) * 64 + l16 * 4 + (quad ^ fxor)) * 8)];
#pragma unroll
        for (int i = 0; i < 4; ++i)
#pragma unroll
            for (int j = 0; j < 4; ++j) acc[i][j] = MFMA16(af[i], bfr[j], acc[i][j]);
    }

    if constexpr (EPI == 0) {
#pragma unroll
        for (int i = 0; i < 4; ++i)
#pragma unroll
            for (int j = 0; j < 4; ++j)
#pragma unroll
                for (int r = 0; r < 4; ++r) {
                    const int row = bm + wy + i * 16 + quad * 4 + r;
                    const int col = bn + wx + j * 16 + l16;
                    ((float*)C)[(size_t)row * N + col] = acc[i][j][r];
                }
    }
}

// ---------------------------------------------------------------------------
// MFMA flash attention, 32x32x16, no-max softmax. 256 threads = 4 waves;
// each wave owns 32 queries -> block = 128 queries; streams 64-key tiles.
// __launch_bounds__(256,3): 3 waves/EU = grid's 3 blocks/CU while allowing
// ~168 VGPR (r3 shipped at 64 VGPR -> remat VALU storm).
// ---------------------------------------------------------------------------
__global__ __launch_bounds__(256, 3) void attn_mfma(const u16* __restrict__ Qh,
                                                    const u16* __restrict__ Kh,
                                                    const u16* __restrict__ Vt,
                                                    u16* __restrict__ AO) {
    __shared__ __align__(16) u16 Ks[2][512 * 8];
    __shared__ __align__(16) u16 Vs[2][512 * 8];

    const int t = threadIdx.x;
    const int wave = t >> 6, lane = t & 63;
    const int l31 = lane & 31, half = lane >> 5;

    // XCD-grouped decode: bid&7 -> XCD slot; 12 (b,h) per XCD; 8 q-blocks each
    const int bid = blockIdx.x;
    const int xcd = bid & 7, idx = bid >> 3;      // idx 0..95
    const int bh = xcd * 12 + (idx % 12);
    const int q0 = (idx / 12) * 128;
    const int b = bh / NHEADS, h = bh - b * NHEADS;

    const u16* Kb = Kh + (size_t)bh * SEQ * HD;
    const u16* Vb = Vt + (size_t)bh * HD * SEQ;
    const int qb = q0 + wave * 32;

    // Q fragments (B-operand: n = query = l31, k = tt*16 + half*8 + j)
    short8 qf[4];
#pragma unroll
    for (int tt = 0; tt < 4; ++tt)
        qf[tt] = *(const short8*)(Qh + ((size_t)bh * SEQ + qb + l31) * HD +
                                  tt * 16 + half * 8);

    f32x16 o[2]; // [d-tile]
#pragma unroll
    for (int dt = 0; dt < 2; ++dt)
#pragma unroll
        for (int r = 0; r < 16; ++r) o[dt][r] = 0.f;
    float lp = 0.f;

    // staging lane->global mapping (inverse of slot swizzle)
    const int arl = lane >> 3;            // row within 8-row span
    const int acc8 = (lane & 7) ^ arl;    // chunk 0..7
    // fragment-read bank spread piece
    const int fx8 = l31 & 7;

    auto stage = [&](int j0, int db) {
#pragma unroll
        for (int it = 0; it < 2; ++it) {
            const int cb = it * 256 + wave * 64; // span base, wave-uniform
            const int r0 = (cb >> 6) * 8 + arl;  // row 0..63
            gl2lds16(Kb + (size_t)(j0 + r0) * HD + acc8 * 8,
                     (char*)Ks[db] + cb * 16);
            gl2lds16(Vb + (size_t)r0 * SEQ + j0 + acc8 * 8,
                     (char*)Vs[db] + cb * 16);
        }
    };

    stage(0, 0);
#pragma unroll 2
    for (int jt = 0; jt < SEQ / 64; ++jt) {
        const int db = jt & 1;
        VM0;   // own tile-jt loads done (issued one full compute phase ago)
        bar(); // all waves' loads landed; all waves done reading buf db^1
        if (jt + 1 < SEQ / 64) stage((jt + 1) * 64, db ^ 1);
        const u16* Ksl = Ks[db];
        const u16* Vsl = Vs[db];

        // ---- S^T: both 32-key tiles, independent MFMA chains first ----
        f32x16 sa0, sa1;
#pragma unroll
        for (int r = 0; r < 16; ++r) { sa0[r] = 0.f; sa1[r] = 0.f; }
#pragma unroll
        for (int tt = 0; tt < 4; ++tt) {
            short8 kf0 = *(const short8*)&Ksl[
                ((((l31 >> 3)) * 64) + fx8 * 8 + ((2 * tt + half) ^ fx8)) * 8];
            short8 kf1 = *(const short8*)&Ksl[
                (((4 + (l31 >> 3)) * 64) + fx8 * 8 + ((2 * tt + half) ^ fx8)) * 8];
            sa0 = MFMA32(kf0, qf[tt], sa0);
            sa1 = MFMA32(kf1, qf[tt], sa1);
        }

        // ---- softmax numerators in-register (exp2 -> cvt_pk -> permlane) ----
        short8 pf0a, pf0b, pf1a, pf1b;
        {
            float p[16];
#pragma unroll
            for (int r = 0; r < 16; ++r) p[r] = EXP2(sa0[r]);
#pragma unroll
            for (int rg = 0; rg < 4; ++rg)
                lp += (p[rg * 4] + p[rg * 4 + 1]) + (p[rg * 4 + 2] + p[rg * 4 + 3]);
            u32 q[8];
#pragma unroll
            for (int i = 0; i < 8; ++i) q[i] = cvtpk(p[2 * i], p[2 * i + 1]);
            u32 d0, d1, d2, d3, e0, e1, e2, e3;
            plswap(q[0], q[2], half, d0, d2);
            plswap(q[1], q[3], half, d1, d3);
            plswap(q[4], q[6], half, e0, e2);
            plswap(q[5], q[7], half, e1, e3);
            u32x4 f0v = {d0, d1, d2, d3};
            u32x4 f1v = {e0, e1, e2, e3};
            pf0a = __builtin_bit_cast(short8, f0v);
            pf0b = __builtin_bit_cast(short8, f1v);
        }
        {
            float p[16];
#pragma unroll
            for (int r = 0; r < 16; ++r) p[r] = EXP2(sa1[r]);
#pragma unroll
            for (int rg = 0; rg < 4; ++rg)
                lp += (p[rg * 4] + p[rg * 4 + 1]) + (p[rg * 4 + 2] + p[rg * 4 + 3]);
            u32 q[8];
#pragma unroll
            for (int i = 0; i < 8; ++i) q[i] = cvtpk(p[2 * i], p[2 * i + 1]);
            u32 d0, d1, d2, d3, e0, e1, e2, e3;
            plswap(q[0], q[2], half, d0, d2);
            plswap(q[1], q[3], half, d1, d3);
            plswap(q[4], q[6], half, e0, e2);
            plswap(q[5], q[7], half, e1, e3);
            u32x4 f0v = {d0, d1, d2, d3};
            u32x4 f1v = {e0, e1, e2, e3};
            pf1a = __builtin_bit_cast(short8, f0v);
            pf1b = __builtin_bit_cast(short8, f1v);
        }

        // ---- PV: O^T += V^T @ P (4 slices of 16 keys) ----
#pragma unroll
        for (int kt = 0; kt < 2; ++kt)
#pragma unroll
            for (int s = 0; s < 2; ++s) {
                short8 pf = kt ? (s ? pf1b : pf1a) : (s ? pf0b : pf0a);
                const int c = kt * 4 + s * 2 + half; // key-slice column
#pragma unroll
                for (int dt = 0; dt < 2; ++dt) {
                    short8 vf = *(const short8*)&Vsl[
                        (((dt * 4 + (l31 >> 3)) * 64) + fx8 * 8 + (c ^ fx8)) * 8];
                    o[dt] = MFMA32(vf, pf, o[dt]);
                }
            }
    }

    // final l reduction (halves hold disjoint key subsets) and output
    const float invl = 1.f / (lp + __shfl_xor(lp, 32, 64));
    u16* ob = AO + (size_t)(b * SEQ + qb + l31) * NDIM + h * HD;
#pragma unroll
    for (int dt = 0; dt < 2; ++dt)
#pragma unroll
        for (int rg = 0; rg < 4; ++rg) {
            bf16x4 ok = {(short)f2bf(o[dt][rg * 4 + 0] * invl),
                         (short)f2bf(o[dt][rg * 4 + 1] * invl),
                         (short)f2bf(o[dt][rg * 4 + 2] * invl),
                         (short)f2bf(o[dt][rg * 4 + 3] * invl)};
            *(bf16x4*)(ob + dt * 32 + rg * 8 + half * 4) = ok;
        }
}

// ---------------------------------------------------------------------------
extern "C" void kernel_launch(void* const* d_in, const int* in_sizes, int n_in,
                              void* d_out, int out_size, void* d_ws, size_t ws_size,
                              hipStream_t stream) {
    const float* x    = (const float*)d_in[0];
    const float* Wq   = (const float*)d_in[1];
    const float* Wk   = (const float*)d_in[2];
    const float* Wv   = (const float*)d_in[3];
    const float* Wo   = (const float*)d_in[4];
    const float* s_qk = (const float*)d_in[5];
    float* out = (float*)d_out;

    char* w = (char*)d_ws;
    const size_t TE = (size_t)MROWS * NDIM;
    u16* xb   = (u16*)w;                    w += TE * 2;
    u16* Wqkv = (u16*)w;                    w += (size_t)3 * NDIM * NDIM * 2;
    u16* Wob  = (u16*)w;                    w += (size_t)NDIM * NDIM * 2;
    u16* Qh   = (u16*)w;                    w += TE * 2;
    u16* Kh   = (u16*)w;                    w += TE * 2;
    u16* Vt   = (u16*)w;                    w += TE * 2;
    u16* ao   = (u16*)w;

    castall<<<6144 + 4 * 576, 256, 0, stream>>>(x, Wq, Wk, Wv, Wo, xb, Wqkv, Wob);

    // Fused QKV projection: 256 full 256^2 tiles (one round) + 128 pipelined
    // quarter tiles that fill the scheduling tail.
    gemm256_qkv<<<384, 512, 0, stream>>>(xb, Wqkv, Vt, s_qk, Qh, Kh);

    // Flash attention, XCD-grouped 1D grid (768 = 8 xcd x 12 bh x 8 qblk)
    attn_mfma<<<768, 256, 0, stream>>>(Qh, Kh, Vt, ao);

    // Output projection: NX = 768/128 = 6
    gemm_bf16<0><<<6 * 64, 256, 0, stream>>>(
        ao, Wob, out, NDIM, nullptr, nullptr, nullptr, 6);
}

// Round 6
// 176.402 us; speedup vs baseline: 1.1524x; 1.0040x over previous
//
#include <hip/hip_runtime.h>
#include <hip/hip_bf16.h>
#include <math.h>

#define NDIM 768
#define NHEADS 12
#define HD 64
#define SEQ 1024
#define BATCH 8
#define MROWS (BATCH * SEQ)          // 8192
#define SQRT_DIM 27.712812921102035f // 1/SCALE_PARAM_INIT
#define LOG2E 1.4426950408889634f

typedef unsigned short u16;
typedef unsigned int u32;
typedef __attribute__((ext_vector_type(8))) short short8;   // 8 bf16 = 4 VGPRs
typedef __attribute__((ext_vector_type(4))) short bf16x4;   // 4 bf16 = 2 VGPRs
typedef __attribute__((ext_vector_type(4))) float f32x4;
typedef __attribute__((ext_vector_type(16))) float f32x16;
typedef __attribute__((ext_vector_type(2))) u32 u32x2;
typedef __attribute__((ext_vector_type(4))) u32 u32x4;

#define MFMA16(a, b, c) __builtin_amdgcn_mfma_f32_16x16x32_bf16(a, b, c, 0, 0, 0)
#define MFMA32(a, b, c) __builtin_amdgcn_mfma_f32_32x32x16_bf16(a, b, c, 0, 0, 0)

#if __has_builtin(__builtin_amdgcn_exp2f)
#define EXP2(x) __builtin_amdgcn_exp2f(x)
#else
#define EXP2(x) exp2f(x)
#endif

__device__ inline u16 f2bf(float f) {
    __hip_bfloat16 h = __float2bfloat16(f);
    return *reinterpret_cast<u16*>(&h);
}

// RNE round a,b to bf16 and pack into one u32 (a = low half). No NaN check —
// callers guarantee finite inputs.
__device__ inline u32 rne_pack(float a, float b) {
    u32 ua = __builtin_bit_cast(u32, a), ub = __builtin_bit_cast(u32, b);
    ua = (ua + 0x7fffu + ((ua >> 16) & 1u)) >> 16;
    ub = (ub + 0x7fffu + ((ub >> 16) & 1u)) >> 16;
    return (ub << 16) | ua;
}

// single-instruction packed f32->bf16 RNE convert (no builtin on gfx950; T12)
__device__ inline u32 cvtpk(float a, float b) {
    u32 r;
    asm("v_cvt_pk_bf16_f32 %0, %1, %2" : "=v"(r) : "v"(a), "v"(b));
    return r;
}

// async 16B global->LDS. LDS dest is wave-uniform base; HW adds lane*16.
__device__ inline void gl2lds16(const void* g, void* l) {
    __builtin_amdgcn_global_load_lds((const __attribute__((address_space(1))) void*)g,
                                     (__attribute__((address_space(3))) void*)l, 16, 0, 0);
}

// compiler-fenced raw barrier (NO vmcnt drain — that is the whole point)
__device__ inline void bar() {
    asm volatile("" ::: "memory");
    __builtin_amdgcn_s_barrier();
    asm volatile("" ::: "memory");
}
#define LGKM0 asm volatile("s_waitcnt lgkmcnt(0)" ::: "memory")
#define VM0   asm volatile("s_waitcnt vmcnt(0)" ::: "memory")

// half-swap: x[i] = i<32 ? a[i] : b[i-32]; y[i] = i<32 ? a[i+32] : b[i].
// One v_permlane32_swap_b32 yields both outputs (T12); shfl fallback.
__device__ inline void plswap(u32 a, u32 b, int half, u32& x, u32& y) {
#if __has_builtin(__builtin_amdgcn_permlane32_swap)
    u32x2 r = __builtin_amdgcn_permlane32_swap(a, b, false, false);
    x = r[0]; y = r[1];
#else
    u32 oa = __shfl_xor(a, 32, 64), ob = __shfl_xor(b, 32, 64);
    x = half ? ob : a;
    y = half ? b : oa;
#endif
}

// ---------------------------------------------------------------------------
// One fused cast kernel: x (6144 blocks) + Wq/Wk/Wv -> Wqkv, Wo -> Wob.
// ---------------------------------------------------------------------------
__global__ __launch_bounds__(256) void castall(const float* __restrict__ x,
                                               const float* __restrict__ Wq,
                                               const float* __restrict__ Wk,
                                               const float* __restrict__ Wv,
                                               const float* __restrict__ Wo,
                                               u16* __restrict__ xb,
                                               u16* __restrict__ Wqkv,
                                               u16* __restrict__ Wob) {
    const int WB = (NDIM * NDIM) / 1024; // 576 blocks per weight
    int blk = blockIdx.x;
    const float* s;
    u16* d;
    int base;
    if (blk < 6144) {
        s = x; d = xb; base = blk * 1024;
    } else {
        int wsel = (blk - 6144) / WB, r = (blk - 6144) % WB;
        base = r * 1024;
        if (wsel == 0)      { s = Wq; d = Wqkv; }
        else if (wsel == 1) { s = Wk; d = Wqkv + NDIM * NDIM; }
        else if (wsel == 2) { s = Wv; d = Wqkv + 2 * NDIM * NDIM; }
        else                { s = Wo; d = Wob; }
    }
    int i = base + threadIdx.x * 4;
    float4 v = *(const float4*)(s + i);
    uint2 o = make_uint2(rne_pack(v.x, v.y), rne_pack(v.z, v.w));
    *(uint2*)(d + i) = o;
}

// ---------------------------------------------------------------------------
// 256x256 / BK=64 / 8-wave 8-phase GEMM (T3+T4+T5 template) for the fused
// QKV projection: C = A[8192,768] @ B[2304,768]^T with fused cosine-norm
// (Q/K) and transposed-V epilogue.
//
// Scheduling: grid = 512:
//   blk 0..255  : full 256^2 tiles over N-tiles 0..7 (exactly one round)
//   blk 256..511: 64x128 tail tiles over the last N-strip (V heads 8..11).
//     r6: r5's 128x128 quarters were LDS-read-THROUGHPUT-bound (96 b128
//     reads/CU/iter ~= 1150 cyc >> 155 cyc MFMA) and used only 128 CUs.
//     256 blocks of 64x128 (wave=32x32: 8 reads + 8 MFMA/iter) cut per-CU
//     LDS traffic to 770 cyc/iter and fill every CU for one short round.
// ---------------------------------------------------------------------------
__global__ __launch_bounds__(512, 2) void gemm256_qkv(const u16* __restrict__ A,
                                                      const u16* __restrict__ B,
                                                      u16* __restrict__ Vt,
                                                      const float* __restrict__ s_qk,
                                                      u16* __restrict__ Qdst,
                                                      u16* __restrict__ Kdst) {
    constexpr int K = NDIM;     // 768
    constexpr int NT = K / 64;  // 12 K-tiles
    __shared__ __align__(16) u16 As[2][2][128 * 64]; // [dbuf][half][r*8+slot]
    __shared__ __align__(16) u16 Bs[2][2][128 * 64];

    const int t = threadIdx.x;
    const int wave = t >> 6, lane = t & 63;
    const int quad = lane >> 4, l16 = lane & 15;
    const int fx = l16 & 7;                  // fragment-read XOR key
    const int blk = blockIdx.x;

    // half-tile stage: 128 rows x 64 k = 16 KB = 512 thr x 2 x 16B.
    const int srow = lane >> 3;
    const int schk = (lane & 7) ^ srow;
    auto stg = [&](const u16* src, u16* dst) {
#pragma unroll
        for (int it = 0; it < 2; ++it) {
            const int cb = it * 512 + wave * 64; // slot base, wave-uniform
            const int r = (cb >> 3) + srow;      // row 0..127
            gl2lds16(src + (size_t)r * K + schk * 8, (char*)dst + cb * 16);
        }
    };

    if (blk < 256) {
        // =================== full 256^2 8-phase path ===================
        const int wm = wave >> 2, wn = wave & 3; // 2 x 4 wave grid, 128x64 each
        const int xcd = blk & 7, local = blk >> 3;            // 0..31
        const int bm = xcd * 1024 + (local >> 3) * 256;       // 4 M-tiles/XCD
        const int bn = (local & 7) * 256;                     // N-tiles 0..7

        f32x4 acc[8][4];
#pragma unroll
        for (int i = 0; i < 8; ++i)
#pragma unroll
            for (int j = 0; j < 4; ++j) acc[i][j] = (f32x4){0.f, 0.f, 0.f, 0.f};

        const u16* Ag = A + (size_t)bm * K;
        const u16* Bg = B + (size_t)bn * K;

        // prologue: tile0 {A,B} + tile1 {B}; wait tile0 (12 issued, 4 may fly)
        stg(Ag,                        As[0][0]);
        stg(Ag + (size_t)128 * K,      As[0][1]);
        stg(Bg,                        Bs[0][0]);
        stg(Bg + (size_t)128 * K,      Bs[0][1]);
        stg(Bg + 64,                   Bs[1][0]);
        stg(Bg + (size_t)128 * K + 64, Bs[1][1]);
        asm volatile("s_waitcnt vmcnt(4)" ::: "memory");
        bar();

        short8 a[4][2], b0[2][2], b1[2][2];
        const int rb0 = (wn & 1) * 64; // this wave's B-row base within its half

#pragma unroll 2
        for (int T = 0; T < NT; ++T) {
            const int db = T & 1;
            u16* Asl = As[db][wm];
            u16* Bsl = Bs[db][wn >> 1];
            const u16* An = Ag + (size_t)(T + 1) * 64;
            const u16* Bn = Bg + (size_t)(T + 2) * 64;

            // ---- P0: read A[mi0-3] + B[ni0-1]; stage A(T+1)h0; MFMA Q(0,0) ----
#pragma unroll
            for (int mi = 0; mi < 4; ++mi) {
                const int r = mi * 16 + l16;
#pragma unroll
                for (int kk = 0; kk < 2; ++kk)
                    a[mi][kk] = *(const short8*)&Asl[(r * 8 + ((kk * 4 + quad) ^ fx)) * 8];
            }
#pragma unroll
            for (int ni = 0; ni < 2; ++ni) {
                const int r = rb0 + ni * 16 + l16;
#pragma unroll
                for (int kk = 0; kk < 2; ++kk)
                    b0[ni][kk] = *(const short8*)&Bsl[(r * 8 + ((kk * 4 + quad) ^ fx)) * 8];
            }
            if (T + 1 < NT) stg(An, As[db ^ 1][0]);
            bar();
            LGKM0;
            __builtin_amdgcn_s_setprio(1);
#pragma unroll
            for (int kk = 0; kk < 2; ++kk)
#pragma unroll
                for (int mi = 0; mi < 4; ++mi)
#pragma unroll
                    for (int ni = 0; ni < 2; ++ni)
                        acc[mi][ni] = MFMA16(a[mi][kk], b0[ni][kk], acc[mi][ni]);
            __builtin_amdgcn_s_setprio(0);
            bar();

            // ---- P1: read B[ni2-3]; stage A(T+1)h1; MFMA Q(0,1) ----
#pragma unroll
            for (int ni = 0; ni < 2; ++ni) {
                const int r = rb0 + (ni + 2) * 16 + l16;
#pragma unroll
                for (int kk = 0; kk < 2; ++kk)
                    b1[ni][kk] = *(const short8*)&Bsl[(r * 8 + ((kk * 4 + quad) ^ fx)) * 8];
            }
            if (T + 1 < NT) stg(An + (size_t)128 * K, As[db ^ 1][1]);
            bar();
            LGKM0;
            __builtin_amdgcn_s_setprio(1);
#pragma unroll
            for (int kk = 0; kk < 2; ++kk)
#pragma unroll
                for (int mi = 0; mi < 4; ++mi)
#pragma unroll
                    for (int ni = 0; ni < 2; ++ni)
                        acc[mi][ni + 2] = MFMA16(a[mi][kk], b1[ni][kk], acc[mi][ni + 2]);
            __builtin_amdgcn_s_setprio(0);
            bar();

            // ---- P2: read A[mi4-7]; stage B(T+2)h0; MFMA Q(1,1) ----
#pragma unroll
            for (int mi = 0; mi < 4; ++mi) {
                const int r = (mi + 4) * 16 + l16;
#pragma unroll
                for (int kk = 0; kk < 2; ++kk)
                    a[mi][kk] = *(const short8*)&Asl[(r * 8 + ((kk * 4 + quad) ^ fx)) * 8];
            }
            if (T + 2 < NT) stg(Bn, Bs[db][0]);
            bar();
            LGKM0;
            __builtin_amdgcn_s_setprio(1);
#pragma unroll
            for (int kk = 0; kk < 2; ++kk)
#pragma unroll
                for (int mi = 0; mi < 4; ++mi)
#pragma unroll
                    for (int ni = 0; ni < 2; ++ni)
                        acc[mi + 4][ni + 2] = MFMA16(a[mi][kk], b1[ni][kk], acc[mi + 4][ni + 2]);
            __builtin_amdgcn_s_setprio(0);
            bar();

            // ---- P3: stage B(T+2)h1; MFMA Q(1,0); counted vmcnt; bar ----
            if (T + 2 < NT) stg(Bn + (size_t)128 * K, Bs[db][1]);
            bar();
            __builtin_amdgcn_s_setprio(1);
#pragma unroll
            for (int kk = 0; kk < 2; ++kk)
#pragma unroll
                for (int mi = 0; mi < 4; ++mi)
#pragma unroll
                    for (int ni = 0; ni < 2; ++ni)
                        acc[mi + 4][ni] = MFMA16(a[mi][kk], b0[ni][kk], acc[mi + 4][ni]);
            __builtin_amdgcn_s_setprio(0);
            if (T + 2 < NT) {
                asm volatile("s_waitcnt vmcnt(4)" ::: "memory"); // tile T+1 resident
            } else {
                VM0; // drains A(NT-1) too (last two iters)
            }
            bar();
        }

        // ---- fused QKV epilogue (wave's 64 cols = exactly one head-group) ----
        const int cg = (bn + wn * 64) >> 6; // 0..31 here
        if (cg >= 2 * NHEADS) {
            // V path: transposed bf16 write, 4 consecutive tokens packed -> 8B
            const int h = cg - 2 * NHEADS;
#pragma unroll
            for (int mi = 0; mi < 8; ++mi) {
                const int row = bm + wm * 128 + mi * 16 + quad * 4; // token base
                const int bb = row >> 10, n0 = row & 1023;
#pragma unroll
                for (int ni = 0; ni < 4; ++ni) {
                    const int dd = ni * 16 + l16;
                    uint2 pk = make_uint2(rne_pack(acc[mi][ni][0], acc[mi][ni][1]),
                                          rne_pack(acc[mi][ni][2], acc[mi][ni][3]));
                    *(uint2*)(Vt + (((size_t)(bb * NHEADS + h) * HD + dd) << 10) + n0) = pk;
                }
            }
        } else {
            const bool isq = cg < NHEADS;
            const int h = isq ? cg : cg - NHEADS;
            u16* dst = isq ? Qdst : Kdst;
            const float ex = isq ? 8.f * LOG2E : 1.f;
            float sq[4];
#pragma unroll
            for (int ni = 0; ni < 4; ++ni)
                sq[ni] = s_qk[h * HD + ni * 16 + l16] * SQRT_DIM * ex;
#pragma unroll
            for (int mi = 0; mi < 8; ++mi)
#pragma unroll
                for (int r = 0; r < 4; ++r) {
                    float ss = 0.f;
#pragma unroll
                    for (int ni = 0; ni < 4; ++ni) ss += acc[mi][ni][r] * acc[mi][ni][r];
                    ss += __shfl_xor(ss, 1, 64);
                    ss += __shfl_xor(ss, 2, 64);
                    ss += __shfl_xor(ss, 4, 64);
                    ss += __shfl_xor(ss, 8, 64);
                    float inv = 1.f / fmaxf(sqrtf(ss), 1e-6f);
                    const int row = bm + wm * 128 + mi * 16 + quad * 4 + r;
                    const int bb = row >> 10, tok = row & 1023;
                    u16* o = dst + ((size_t)(bb * NHEADS + h) * SEQ + tok) * HD;
#pragma unroll
                    for (int ni = 0; ni < 4; ++ni)
                        o[ni * 16 + l16] = f2bf(acc[mi][ni][r] * sq[ni] * inv);
                }
        }
    } else {
        // ===== tail: 64x128 tiles, 4-deep ring, counted vmcnt, 256 blocks ====
        const int q = blk - 256;                   // 0..255
        const int bm = (q >> 1) * 64;              // 128 M-slices of 64 rows
        const int bnq = (q & 1) * 128;             // column half of the V strip
        const int wm = wave >> 2, wn = wave & 3;   // 2M x 4N waves, 32x32 each
        const u16* Aq = A + (size_t)bm * K;
        const u16* Bq = B + (size_t)(2048 + bnq) * K;
        u16* Ar = &As[0][0][0]; // ring: 4 slots x 4096 u16 (8 KB A-tile)
        u16* Br = &Bs[0][0][0]; // ring: 4 slots x 8192 u16 (16 KB B-tile)

        f32x4 qa[2][2];
#pragma unroll
        for (int i = 0; i < 2; ++i)
#pragma unroll
            for (int j = 0; j < 2; ++j) qa[i][j] = (f32x4){0.f, 0.f, 0.f, 0.f};

        // A half-stage: 64 rows x 64 k = 8 KB = 512 thr x 1 x 16B
        auto stgA = [&](const u16* src, u16* dst) {
            const int cb = wave * 64;           // slot base, wave-uniform
            const int r = (cb >> 3) + srow;     // row 0..63 (= wave*8 + srow)
            gl2lds16(src + (size_t)r * K + schk * 8, (char*)dst + cb * 16);
        };

        // prologue: stage tiles 0,1,2 (9 loads/thread: 3 per tile = 1A + 2B)
        stgA(Aq,       Ar);
        stg (Bq,       Br);
        stgA(Aq + 64,  Ar + 4096);
        stg (Bq + 64,  Br + 8192);
        stgA(Aq + 128, Ar + 2 * 4096);
        stg (Bq + 128, Br + 2 * 8192);

#pragma unroll
        for (int T = 0; T < NT; ++T) {
            // tile T resident when <= 2 newer tiles (6 loads) remain in flight
            if (T + 2 < NT)      asm volatile("s_waitcnt vmcnt(6)" ::: "memory");
            else if (T + 1 < NT) asm volatile("s_waitcnt vmcnt(3)" ::: "memory");
            else                 VM0;
            bar(); // all waves' tile-T loads landed; slot (T+3)&3 free
            if (T + 3 < NT) {
                stgA(Aq + (size_t)(T + 3) * 64, Ar + ((T + 3) & 3) * 4096);
                stg (Bq + (size_t)(T + 3) * 64, Br + ((T + 3) & 3) * 8192);
            }
            const u16* Asl = Ar + (T & 3) * 4096;
            const u16* Bsl = Br + (T & 3) * 8192;
            short8 af[2][2], bf[2][2];
#pragma unroll
            for (int mi = 0; mi < 2; ++mi) {
                const int r = wm * 32 + mi * 16 + l16;
#pragma unroll
                for (int kk = 0; kk < 2; ++kk)
                    af[mi][kk] = *(const short8*)&Asl[(r * 8 + ((kk * 4 + quad) ^ fx)) * 8];
            }
#pragma unroll
            for (int ni = 0; ni < 2; ++ni) {
                const int r = wn * 32 + ni * 16 + l16;
#pragma unroll
                for (int kk = 0; kk < 2; ++kk)
                    bf[ni][kk] = *(const short8*)&Bsl[(r * 8 + ((kk * 4 + quad) ^ fx)) * 8];
            }
            __builtin_amdgcn_s_setprio(1);
#pragma unroll
            for (int kk = 0; kk < 2; ++kk)
#pragma unroll
                for (int mi = 0; mi < 2; ++mi)
#pragma unroll
                    for (int ni = 0; ni < 2; ++ni)
                        qa[mi][ni] = MFMA16(af[mi][kk], bf[ni][kk], qa[mi][ni]);
            __builtin_amdgcn_s_setprio(0);
        }

        // V epilogue (transposed, 4 tokens packed -> 8B), heads 8..11
#pragma unroll
        for (int mi = 0; mi < 2; ++mi) {
            const int row = bm + wm * 32 + mi * 16 + quad * 4;
            const int bb = row >> 10, n0 = row & 1023;
#pragma unroll
            for (int ni = 0; ni < 2; ++ni) {
                const int cv = bnq + wn * 32 + ni * 16 + l16; // 0..255 in V strip
                const int h = 8 + (cv >> 6), dd = cv & 63;
                uint2 pk = make_uint2(rne_pack(qa[mi][ni][0], qa[mi][ni][1]),
                                      rne_pack(qa[mi][ni][2], qa[mi][ni][3]));
                *(uint2*)(Vt + (((size_t)(bb * NHEADS + h) * HD + dd) << 10) + n0) = pk;
            }
        }
    }
}

// ---------------------------------------------------------------------------
// bf16 MFMA GEMM: C = A[M,768] @ B[N,768]^T, fp32 accum. 128x128 tile,
// double-buffered BK=32 (one barrier/iter). Kept for the output projection.
// ---------------------------------------------------------------------------
template <int EPI>
__global__ __launch_bounds__(256) void gemm_bf16(const u16* __restrict__ A,
                                                 const u16* __restrict__ B,
                                                 void* __restrict__ C, int N,
                                                 const float* __restrict__ s_qk,
                                                 u16* __restrict__ Qdst,
                                                 u16* __restrict__ Kdst,
                                                 int NX) {
    constexpr int K = NDIM;
    constexpr int NKT = K / 32; // 24 K-tiles
    __shared__ __align__(16) u16 As[2][4096]; // 8 KB per buffer
    __shared__ __align__(16) u16 Bs[2][4096];
    const int t = threadIdx.x;
    const int wave = t >> 6, lane = t & 63;
    const int quad = lane >> 4, l16 = lane & 15;
    const int wx = (wave & 1) * 64, wy = (wave >> 1) * 64;
    const int blk = blockIdx.x;
    const int xcd = blk & 7, local = blk >> 3;
    const int bm = (xcd * 8 + local / NX) * 128;
    const int bn = (local % NX) * 128;

    f32x4 acc[4][4];
#pragma unroll
    for (int i = 0; i < 4; ++i)
#pragma unroll
        for (int j = 0; j < 4; ++j) acc[i][j] = (f32x4){0.f, 0.f, 0.f, 0.f};

    const int srl = lane >> 2;
    const int skc = (lane & 3) ^ ((lane >> 3) & 3);
    auto stage = [&](int k0, int bsel) {
#pragma unroll
        for (int it = 0; it < 2; ++it) {
            const int cb = it * 256 + wave * 64;
            const int row = (cb >> 6) * 16 + srl;
            gl2lds16(A + (size_t)(bm + row) * K + k0 + skc * 8,
                     (char*)As[bsel] + cb * 16);
            gl2lds16(B + (size_t)(bn + row) * K + k0 + skc * 8,
                     (char*)Bs[bsel] + cb * 16);
        }
    };
    const int fxor = (l16 >> 1) & 3;

    stage(0, 0);
#pragma unroll
    for (int kt = 0; kt < NKT; ++kt) {
        __syncthreads();
        if (kt + 1 < NKT) stage((kt + 1) * 32, (kt + 1) & 1);
        const int b = kt & 1;
        short8 af[4], bfr[4];
#pragma unroll
        for (int i = 0; i < 4; ++i)
            af[i] = *(const short8*)&As[b][
                ((((wy >> 4) + i) * 64 + l16 * 4 + (quad ^ fxor)) * 8)];
#pragma unroll
        for (int j = 0; j < 4; ++j)
            bfr[j] = *(const short8*)&Bs[b][
                ((((wx >> 4) + j) * 64 + l16 * 4 + (quad ^ fxor)) * 8)];
#pragma unroll
        for (int i = 0; i < 4; ++i)
#pragma unroll
            for (int j = 0; j < 4; ++j) acc[i][j] = MFMA16(af[i], bfr[j], acc[i][j]);
    }

    if constexpr (EPI == 0) {
#pragma unroll
        for (int i = 0; i < 4; ++i)
#pragma unroll
            for (int j = 0; j < 4; ++j)
#pragma unroll
                for (int r = 0; r < 4; ++r) {
                    const int row = bm + wy + i * 16 + quad * 4 + r;
                    const int col = bn + wx + j * 16 + l16;
                    ((float*)C)[(size_t)row * N + col] = acc[i][j][r];
                }
    }
}

// ---------------------------------------------------------------------------
// MFMA flash attention, 32x32x16, no-max softmax. 256 threads = 4 waves;
// each wave owns 32 queries -> block = 128 queries; streams 64-key tiles.
// __launch_bounds__(256,3): 3 waves/EU = grid's 3 blocks/CU while allowing
// ~168 VGPR (r3 shipped at 64 VGPR -> remat VALU storm).
// ---------------------------------------------------------------------------
__global__ __launch_bounds__(256, 3) void attn_mfma(const u16* __restrict__ Qh,
                                                    const u16* __restrict__ Kh,
                                                    const u16* __restrict__ Vt,
                                                    u16* __restrict__ AO) {
    __shared__ __align__(16) u16 Ks[2][512 * 8];
    __shared__ __align__(16) u16 Vs[2][512 * 8];

    const int t = threadIdx.x;
    const int wave = t >> 6, lane = t & 63;
    const int l31 = lane & 31, half = lane >> 5;

    // XCD-grouped decode: bid&7 -> XCD slot; 12 (b,h) per XCD; 8 q-blocks each
    const int bid = blockIdx.x;
    const int xcd = bid & 7, idx = bid >> 3;      // idx 0..95
    const int bh = xcd * 12 + (idx % 12);
    const int q0 = (idx / 12) * 128;
    const int b = bh / NHEADS, h = bh - b * NHEADS;

    const u16* Kb = Kh + (size_t)bh * SEQ * HD;
    const u16* Vb = Vt + (size_t)bh * HD * SEQ;
    const int qb = q0 + wave * 32;

    // Q fragments (B-operand: n = query = l31, k = tt*16 + half*8 + j)
    short8 qf[4];
#pragma unroll
    for (int tt = 0; tt < 4; ++tt)
        qf[tt] = *(const short8*)(Qh + ((size_t)bh * SEQ + qb + l31) * HD +
                                  tt * 16 + half * 8);

    f32x16 o[2]; // [d-tile]
#pragma unroll
    for (int dt = 0; dt < 2; ++dt)
#pragma unroll
        for (int r = 0; r < 16; ++r) o[dt][r] = 0.f;
    float lp = 0.f;

    // staging lane->global mapping (inverse of slot swizzle)
    const int arl = lane >> 3;            // row within 8-row span
    const int acc8 = (lane & 7) ^ arl;    // chunk 0..7
    // fragment-read bank spread piece
    const int fx8 = l31 & 7;

    auto stage = [&](int j0, int db) {
#pragma unroll
        for (int it = 0; it < 2; ++it) {
            const int cb = it * 256 + wave * 64; // span base, wave-uniform
            const int r0 = (cb >> 6) * 8 + arl;  // row 0..63
            gl2lds16(Kb + (size_t)(j0 + r0) * HD + acc8 * 8,
                     (char*)Ks[db] + cb * 16);
            gl2lds16(Vb + (size_t)r0 * SEQ + j0 + acc8 * 8,
                     (char*)Vs[db] + cb * 16);
        }
    };

    stage(0, 0);
#pragma unroll 2
    for (int jt = 0; jt < SEQ / 64; ++jt) {
        const int db = jt & 1;
        VM0;   // own tile-jt loads done (issued one full compute phase ago)
        bar(); // all waves' loads landed; all waves done reading buf db^1
        if (jt + 1 < SEQ / 64) stage((jt + 1) * 64, db ^ 1);
        const u16* Ksl = Ks[db];
        const u16* Vsl = Vs[db];

        // ---- S^T: both 32-key tiles, independent MFMA chains first ----
        f32x16 sa0, sa1;
#pragma unroll
        for (int r = 0; r < 16; ++r) { sa0[r] = 0.f; sa1[r] = 0.f; }
#pragma unroll
        for (int tt = 0; tt < 4; ++tt) {
            short8 kf0 = *(const short8*)&Ksl[
                ((((l31 >> 3)) * 64) + fx8 * 8 + ((2 * tt + half) ^ fx8)) * 8];
            short8 kf1 = *(const short8*)&Ksl[
                (((4 + (l31 >> 3)) * 64) + fx8 * 8 + ((2 * tt + half) ^ fx8)) * 8];
            sa0 = MFMA32(kf0, qf[tt], sa0);
            sa1 = MFMA32(kf1, qf[tt], sa1);
        }

        // ---- softmax numerators in-register (exp2 -> cvt_pk -> permlane) ----
        short8 pf0a, pf0b, pf1a, pf1b;
        {
            float p[16];
#pragma unroll
            for (int r = 0; r < 16; ++r) p[r] = EXP2(sa0[r]);
#pragma unroll
            for (int rg = 0; rg < 4; ++rg)
                lp += (p[rg * 4] + p[rg * 4 + 1]) + (p[rg * 4 + 2] + p[rg * 4 + 3]);
            u32 q[8];
#pragma unroll
            for (int i = 0; i < 8; ++i) q[i] = cvtpk(p[2 * i], p[2 * i + 1]);
            u32 d0, d1, d2, d3, e0, e1, e2, e3;
            plswap(q[0], q[2], half, d0, d2);
            plswap(q[1], q[3], half, d1, d3);
            plswap(q[4], q[6], half, e0, e2);
            plswap(q[5], q[7], half, e1, e3);
            u32x4 f0v = {d0, d1, d2, d3};
            u32x4 f1v = {e0, e1, e2, e3};
            pf0a = __builtin_bit_cast(short8, f0v);
            pf0b = __builtin_bit_cast(short8, f1v);
        }
        {
            float p[16];
#pragma unroll
            for (int r = 0; r < 16; ++r) p[r] = EXP2(sa1[r]);
#pragma unroll
            for (int rg = 0; rg < 4; ++rg)
                lp += (p[rg * 4] + p[rg * 4 + 1]) + (p[rg * 4 + 2] + p[rg * 4 + 3]);
            u32 q[8];
#pragma unroll
            for (int i = 0; i < 8; ++i) q[i] = cvtpk(p[2 * i], p[2 * i + 1]);
            u32 d0, d1, d2, d3, e0, e1, e2, e3;
            plswap(q[0], q[2], half, d0, d2);
            plswap(q[1], q[3], half, d1, d3);
            plswap(q[4], q[6], half, e0, e2);
            plswap(q[5], q[7], half, e1, e3);
            u32x4 f0v = {d0, d1, d2, d3};
            u32x4 f1v = {e0, e1, e2, e3};
            pf1a = __builtin_bit_cast(short8, f0v);
            pf1b = __builtin_bit_cast(short8, f1v);
        }

        // ---- PV: O^T += V^T @ P (4 slices of 16 keys) ----
#pragma unroll
        for (int kt = 0; kt < 2; ++kt)
#pragma unroll
            for (int s = 0; s < 2; ++s) {
                short8 pf = kt ? (s ? pf1b : pf1a) : (s ? pf0b : pf0a);
                const int c = kt * 4 + s * 2 + half; // key-slice column
#pragma unroll
                for (int dt = 0; dt < 2; ++dt) {
                    short8 vf = *(const short8*)&Vsl[
                        (((dt * 4 + (l31 >> 3)) * 64) + fx8 * 8 + (c ^ fx8)) * 8];
                    o[dt] = MFMA32(vf, pf, o[dt]);
                }
            }
    }

    // final l reduction (halves hold disjoint key subsets) and output
    const float invl = 1.f / (lp + __shfl_xor(lp, 32, 64));
    u16* ob = AO + (size_t)(b * SEQ + qb + l31) * NDIM + h * HD;
#pragma unroll
    for (int dt = 0; dt < 2; ++dt)
#pragma unroll
        for (int rg = 0; rg < 4; ++rg) {
            bf16x4 ok = {(short)f2bf(o[dt][rg * 4 + 0] * invl),
                         (short)f2bf(o[dt][rg * 4 + 1] * invl),
                         (short)f2bf(o[dt][rg * 4 + 2] * invl),
                         (short)f2bf(o[dt][rg * 4 + 3] * invl)};
            *(bf16x4*)(ob + dt * 32 + rg * 8 + half * 4) = ok;
        }
}

// ---------------------------------------------------------------------------
extern "C" void kernel_launch(void* const* d_in, const int* in_sizes, int n_in,
                              void* d_out, int out_size, void* d_ws, size_t ws_size,
                              hipStream_t stream) {
    const float* x    = (const float*)d_in[0];
    const float* Wq   = (const float*)d_in[1];
    const float* Wk   = (const float*)d_in[2];
    const float* Wv   = (const float*)d_in[3];
    const float* Wo   = (const float*)d_in[4];
    const float* s_qk = (const float*)d_in[5];
    float* out = (float*)d_out;

    char* w = (char*)d_ws;
    const size_t TE = (size_t)MROWS * NDIM;
    u16* xb   = (u16*)w;                    w += TE * 2;
    u16* Wqkv = (u16*)w;                    w += (size_t)3 * NDIM * NDIM * 2;
    u16* Wob  = (u16*)w;                    w += (size_t)NDIM * NDIM * 2;
    u16* Qh   = (u16*)w;                    w += TE * 2;
    u16* Kh   = (u16*)w;                    w += TE * 2;
    u16* Vt   = (u16*)w;                    w += TE * 2;
    u16* ao   = (u16*)w;

    castall<<<6144 + 4 * 576, 256, 0, stream>>>(x, Wq, Wk, Wv, Wo, xb, Wqkv, Wob);

    // Fused QKV projection: 256 full 256^2 tiles (one round) + 256 small
    // 64x128 tail tiles (one backfill round covering every CU).
    gemm256_qkv<<<512, 512, 0, stream>>>(xb, Wqkv, Vt, s_qk, Qh, Kh);

    // Flash attention, XCD-grouped 1D grid (768 = 8 xcd x 12 bh x 8 qblk)
    attn_mfma<<<768, 256, 0, stream>>>(Qh, Kh, Vt, ao);

    // Output projection: NX = 768/128 = 6
    gemm_bf16<0><<<6 * 64, 256, 0, stream>>>(
        ao, Wob, out, NDIM, nullptr, nullptr, nullptr, 6);
}